// Round 9
// baseline (2108.036 us; speedup 1.0000x reference)
//
#include <hip/hip_runtime.h>

#define BB 32
#define CC 128
#define HH 12
#define WW 1200
#define DIN 1536
#define FIXD 768
#define OVL 4
#define GG 6
#define DD 512
#define KK 1024
#define TT 300
#define NV 9600        /* B*T vectors per group */
#define MROWS 38400    /* B*W */

// workspace layout (float offsets)
#define Y_OFF     0          /* 29,491,200 floats; Tab overlays this after k_dist2 */
#define ET_OFF    29491200
#define NORM_OFF  32636928
#define BEST_OFF  32643072   /* 57600 uint64 = 115200 floats */
#define LOSS_OFF  32758272
#define ZN_OFF    32758336   /* 57600 floats */

// LDS column swizzle for B-side tiles (placement-only)
#define BSWZ(c) ((c) + 4 * ((c) >> 5))

typedef unsigned int u32;

// ---------------- K1: proj_down fp32 GEMM, 128x128 tile, 8x8/thread ----------
// Y[n][f] = sum_k z[b*1843200 + k*1200 + w] * w_down[f*1536+k];  n = b*1200+w
// Accumulation is strictly k-sequential per output -> bit-identical Y to
// R3/R5/R6/R8 (argmin-critical: do NOT change the fmaf chain order).
// A-staging uses async global->LDS DMA: dest = wave-uniform base + lane*4
// (As[kk][arow] with arow lane-linear), global src per-lane (per-row b decode).
__global__ __launch_bounds__(256) void k_gemm_down(const float* __restrict__ z,
                                                   const float* __restrict__ w_down,
                                                   float* __restrict__ Y) {
    __shared__ float As[16][132];
    __shared__ float Bs[16][140];
    const int n0 = blockIdx.y * 128, f0 = blockIdx.x * 128;
    const int tid = threadIdx.x;
    // A staging: row fixed per thread (128 rows), 8 k-slots (k = ak0 + 2*i)
    const int arow = tid & 127;
    const int ak0 = tid >> 7;           // 0..1 (wave-pair uniform)
    const int wrow = ((tid >> 6) & 1) << 6;   // 0 or 64: wave-uniform LDS row base
    const int nA = n0 + arow;
    const int bA = nA / WW, wA = nA - bA * WW;
    const size_t zbase = (size_t)bA * (CC * HH * WW) + wA;
    // B staging: col = tid>>1 (128 cols), two float4 (q = bq, bq+2)
    const int bcol = tid >> 1, bq = tid & 1;
    const int bsc = BSWZ(bcol);
    // compute thread grid 16x16
    const int trow = tid >> 4, tcol = tid & 15;
    const int bread = tcol * 8 + 4 * (tcol >> 2);
    float acc[8][8] = {};
    for (int kt = 0; kt < DIN; kt += 16) {
        // A: async DMA, 8 rows of 16-k slab (issues immediately, drains at barrier)
        #pragma unroll
        for (int i = 0; i < 8; i++) {
            const int kk = ak0 + i * 2;
            __builtin_amdgcn_global_load_lds(
                (const __attribute__((address_space(1))) u32*)&z[zbase + (size_t)(kt + kk) * WW],
                (__attribute__((address_space(3))) u32*)&As[kk][wrow],
                4, 0, 0);
        }
        // B: VGPR path (transposed store, not lane-linear)
        #pragma unroll
        for (int i = 0; i < 2; i++) {
            const int q = bq + i * 2;
            const float4 v = *(const float4*)&w_down[(size_t)(f0 + bcol) * DIN + kt + q * 4];
            Bs[q * 4 + 0][bsc] = v.x;
            Bs[q * 4 + 1][bsc] = v.y;
            Bs[q * 4 + 2][bsc] = v.z;
            Bs[q * 4 + 3][bsc] = v.w;
        }
        __syncthreads();
        #pragma unroll
        for (int k = 0; k < 16; k++) {
            float av[8], bv[8];
            *(float4*)&av[0] = *(const float4*)&As[k][trow * 8];
            *(float4*)&av[4] = *(const float4*)&As[k][trow * 8 + 4];
            *(float4*)&bv[0] = *(const float4*)&Bs[k][bread];
            *(float4*)&bv[4] = *(const float4*)&Bs[k][bread + 4];
            #pragma unroll
            for (int i = 0; i < 8; i++)
                #pragma unroll
                for (int j = 0; j < 8; j++)
                    acc[i][j] = fmaf(av[i], bv[j], acc[i][j]);
        }
        __syncthreads();
    }
    #pragma unroll
    for (int i = 0; i < 8; i++) {
        float4 o0, o1;
        o0.x = acc[i][0]; o0.y = acc[i][1]; o0.z = acc[i][2]; o0.w = acc[i][3];
        o1.x = acc[i][4]; o1.y = acc[i][5]; o1.z = acc[i][6]; o1.w = acc[i][7];
        float* yr = &Y[(size_t)(n0 + trow * 8 + i) * FIXD + f0 + tcol * 8];
        *(float4*)yr = o0;
        *(float4*)(yr + 4) = o1;
    }
}

// ---------------- K2: transpose codebook emb(g,d,k) -> ET(g,k,d) ----------------
__global__ __launch_bounds__(256) void k_transpose(const float* __restrict__ emb,
                                                   float* __restrict__ ET) {
    int i = blockIdx.x * 256 + threadIdx.x;
    if (i >= GG * KK * DD) return;
    int d = i & 511;
    int rem = i >> 9;
    int k = rem & 1023;
    int g = rem >> 10;
    ET[i] = emb[((g * DD + d) << 10) + k];
}

// ---------------- K2b: per-code squared norms (fp64 accumulate) ----------------
__global__ __launch_bounds__(64) void k_norms(const float* __restrict__ ET,
                                              float* __restrict__ norms) {
    const int code = blockIdx.x;
    const int lane = threadIdx.x;
    const float* row = ET + code * DD;
    double s = 0.0;
    #pragma unroll
    for (int r = 0; r < 8; r++) {
        float v = row[lane + r * 64];
        s += (double)v * (double)v;
    }
    #pragma unroll
    for (int off = 32; off; off >>= 1) s += __shfl_down(s, off);
    if (lane == 0) norms[code] = (float)s;
}

// ---------------- K3: distance GEMM + fused argmin + znorm fold --------------
// Scores are exact-fp32, d-sequential -> bit-identical to R5/R6/R8
// (argmin-critical). launch_bounds(256,6) caps VGPR at ~85 to raise occupancy.
__global__ __launch_bounds__(256, 6) void k_dist2(const float* __restrict__ Y,
                                                  const float* __restrict__ ET,
                                                  const float* __restrict__ norms,
                                                  unsigned long long* __restrict__ best,
                                                  float* __restrict__ znorm) {
    __shared__ float Zs[16][68];
    __shared__ float Es[16][140];
    __shared__ unsigned long long red[64][17];
    const int r = blockIdx.x;            // 0..1199
    const int g = blockIdx.y;            // 0..5
    const int chunk = r / 48;            // 25 chunks
    const int wi = r - chunk * 48;       // 0..47
    const int vt = chunk * 6 + (wi % 6); // 0..149
    const int ct = wi / 6;               // 0..7
    const int tid = threadIdx.x;
    const int rgrp = tid >> 4, cgrp = tid & 15;
    const int rbase = rgrp * 4;
    const int eread = cgrp * 8 + 4 * (cgrp >> 2);
    const int v0 = vt * 64, c0 = ct * 128;
    const float* ETg = ET + (size_t)g * KK * DD;

    const int zrow = tid >> 2, zq = tid & 3;
    const int vz = v0 + zrow;
    const int bz = vz / TT, tz = vz - bz * TT;

    float acc[4][8] = {};
    float zs = 0.0f;

    for (int kt = 0; kt < DD; kt += 16) {
        const int p0 = g * DD + kt;
        const int s = p0 / FIXD, f0 = p0 - s * FIXD;
        {
            const float4 v = *(const float4*)&Y[(bz * WW + tz * OVL + s) * FIXD + f0 + zq * 4];
            Zs[zq * 4 + 0][zrow] = v.x;
            Zs[zq * 4 + 1][zrow] = v.y;
            Zs[zq * 4 + 2][zrow] = v.z;
            Zs[zq * 4 + 3][zrow] = v.w;
            if (ct == 0) {
                zs = fmaf(v.x, v.x, zs);
                zs = fmaf(v.y, v.y, zs);
                zs = fmaf(v.z, v.z, zs);
                zs = fmaf(v.w, v.w, zs);
            }
        }
        #pragma unroll
        for (int i = 0; i < 2; i++) {
            int flat = tid + i * 256;
            int code = flat >> 2, q = flat & 3;
            const int sc = BSWZ(code);
            const float4 v = *(const float4*)&ETg[(size_t)(c0 + code) * DD + kt + q * 4];
            Es[q * 4 + 0][sc] = v.x;
            Es[q * 4 + 1][sc] = v.y;
            Es[q * 4 + 2][sc] = v.z;
            Es[q * 4 + 3][sc] = v.w;
        }
        __syncthreads();
        #pragma unroll
        for (int k = 0; k < 16; k++) {
            const float4 z4 = *(const float4*)&Zs[k][rbase];
            const float4 ea = *(const float4*)&Es[k][eread];
            const float4 eb = *(const float4*)&Es[k][eread + 4];
            const float zv[4] = {z4.x, z4.y, z4.z, z4.w};
            const float ev[8] = {ea.x, ea.y, ea.z, ea.w, eb.x, eb.y, eb.z, eb.w};
            #pragma unroll
            for (int i = 0; i < 4; i++)
                #pragma unroll
                for (int j = 0; j < 8; j++)
                    acc[i][j] = fmaf(zv[i], ev[j], acc[i][j]);
        }
        __syncthreads();
    }

    if (ct == 0) {
        float zsum = zs;
        zsum += __shfl_down(zsum, 2);
        zsum += __shfl_down(zsum, 1);
        if (zq == 0) znorm[g * NV + v0 + zrow] = zsum;
    }

    unsigned long long kbest[4];
    #pragma unroll
    for (int i = 0; i < 4; i++) kbest[i] = ~0ull;
    #pragma unroll
    for (int j = 0; j < 8; j++) {
        const int c = c0 + cgrp * 8 + j;
        const float nrm = norms[(g << 10) + c];
        #pragma unroll
        for (int i = 0; i < 4; i++) {
            float score = nrm - 2.0f * acc[i][j];
            unsigned u = __float_as_uint(score);
            u = (u & 0x80000000u) ? ~u : (u | 0x80000000u);
            unsigned long long key = ((unsigned long long)u << 32) | (unsigned)c;
            if (key < kbest[i]) kbest[i] = key;
        }
    }
    #pragma unroll
    for (int i = 0; i < 4; i++) red[rbase + i][cgrp] = kbest[i];
    __syncthreads();
    if (tid < 64) {
        unsigned long long b = red[tid][0];
        #pragma unroll
        for (int j = 1; j < 16; j++) {
            unsigned long long v = red[tid][j];
            if (v < b) b = v;
        }
        atomicMin(&best[g * NV + v0 + tid], b);
    }
}

// ---------------- K4: loss = sum_v (best_score_v + |z_v|^2) ------------------
__global__ __launch_bounds__(256) void k_sumloss(const unsigned long long* __restrict__ best,
                                                 const float* __restrict__ znorm,
                                                 float* __restrict__ lossAcc) {
    const int v = blockIdx.x * 256 + threadIdx.x;        // 225 blocks * 256 = 57600
    const unsigned long long key = best[v];
    const unsigned u = (unsigned)(key >> 32);
    const unsigned x = (u & 0x80000000u) ? (u & 0x7fffffffu) : ~u;
    float s = __uint_as_float(x) + znorm[v];
    __shared__ float red[256];
    red[threadIdx.x] = s;
    __syncthreads();
    for (int off = 128; off; off >>= 1) {
        if (threadIdx.x < off) red[threadIdx.x] += red[threadIdx.x + off];
        __syncthreads();
    }
    if (threadIdx.x == 0) atomicAdd(lossAcc, red[0]);
}

// ---------------- K5a: per-(segment,code) up-projection table ----------------
__constant__ int SEG_G[8]  = {0, 1, 1, 2, 3, 4, 4, 5};
__constant__ int SEG_D0[8] = {0, 0, 256, 0, 0, 0, 256, 0};
__constant__ int SEG_L[8]  = {512, 256, 256, 512, 512, 256, 256, 512};
__constant__ int SEG_F0[8] = {0, 512, 0, 256, 0, 512, 0, 256};

__global__ __launch_bounds__(256) void k_table(const float* __restrict__ ET,
                                               const float* __restrict__ w_up,
                                               float* __restrict__ Tab) {
    __shared__ float As[16][68];
    __shared__ float Bs[16][140];
    const int bm = blockIdx.x;
    const int bn = blockIdx.y;
    const int seg = blockIdx.z;
    const int g = SEG_G[seg], d0 = SEG_D0[seg], len = SEG_L[seg], fb = SEG_F0[seg];
    const int tid = threadIdx.x;
    const int k0 = bm * 64, dout0 = bn * 128;
    const int arow = tid >> 2, aq = tid & 3;
    const int rbase = (tid >> 4) << 2;
    const int cgrp = tid & 15;
    const int bread = cgrp * 8 + 4 * (cgrp >> 2);
    const float* ETg = ET + (size_t)(g << 10) * DD;
    float acc[4][8] = {};
    for (int kt = 0; kt < len; kt += 16) {
        {
            const float4 v = *(const float4*)&ETg[(size_t)(k0 + arow) * DD + d0 + kt + aq * 4];
            As[aq * 4 + 0][arow] = v.x;
            As[aq * 4 + 1][arow] = v.y;
            As[aq * 4 + 2][arow] = v.z;
            As[aq * 4 + 3][arow] = v.w;
        }
        #pragma unroll
        for (int i = 0; i < 2; i++) {
            int fl = tid + i * 256;
            int col = fl >> 2, q = fl & 3;
            const int sc = BSWZ(col);
            const float4 v = *(const float4*)&w_up[(size_t)(dout0 + col) * FIXD + fb + kt + q * 4];
            Bs[q * 4 + 0][sc] = v.x;
            Bs[q * 4 + 1][sc] = v.y;
            Bs[q * 4 + 2][sc] = v.z;
            Bs[q * 4 + 3][sc] = v.w;
        }
        __syncthreads();
        #pragma unroll
        for (int k = 0; k < 16; k++) {
            const float4 a  = *(const float4*)&As[k][rbase];
            const float4 ba = *(const float4*)&Bs[k][bread];
            const float4 bb = *(const float4*)&Bs[k][bread + 4];
            const float av[4] = {a.x, a.y, a.z, a.w};
            const float bv[8] = {ba.x, ba.y, ba.z, ba.w, bb.x, bb.y, bb.z, bb.w};
            #pragma unroll
            for (int i = 0; i < 4; i++)
                #pragma unroll
                for (int j = 0; j < 8; j++)
                    acc[i][j] = fmaf(av[i], bv[j], acc[i][j]);
        }
        __syncthreads();
    }
    #pragma unroll
    for (int i = 0; i < 4; i++) {
        float4 o0, o1;
        o0.x = acc[i][0]; o0.y = acc[i][1]; o0.z = acc[i][2]; o0.w = acc[i][3];
        o1.x = acc[i][4]; o1.y = acc[i][5]; o1.z = acc[i][6]; o1.w = acc[i][7];
        float* tr = &Tab[(size_t)((seg << 10) + k0 + rbase + i) * DIN + dout0 + cgrp * 8];
        *(float4*)tr = o0;
        *(float4*)(tr + 4) = o1;
    }
}

// ---------------- K5b: gather-add scatter to output ----------------
__global__ __launch_bounds__(256) void k_scatter(const float* __restrict__ Tab,
                                                 const unsigned long long* __restrict__ best,
                                                 float* __restrict__ out) {
    __shared__ float Ls[64][65];
    const int dt = blockIdx.x;
    const int wt = blockIdx.y;
    const int b  = blockIdx.z;
    const int dout0 = dt * 64, w0 = wt * 64;
    const int wlim = (WW - w0 < 64) ? (WW - w0) : 64;
    const int tid = threadIdx.x;
    const int wi = tid >> 2, q = tid & 3;

    if (wi < wlim) {
        const int w = w0 + wi;
        const int s = w & 3;
        const int t = w >> 2;
        const int gEt[4] = {0, 1, 3, 4};
        const int gOt[4] = {1, 2, 4, 5};
        int ce = (int)(unsigned)best[gEt[s] * NV + b * TT + t];
        int co = (int)(unsigned)best[gOt[s] * NV + b * TT + t];
        size_t rowE = (size_t)(((2 * s) << 10) + ce) * DIN;
        size_t rowO = (size_t)(((2 * s + 1) << 10) + co) * DIN;
        #pragma unroll
        for (int rep = 0; rep < 4; rep++) {
            const int doff = rep * 16 + q * 4;
            const float4 a = *(const float4*)&Tab[rowE + dout0 + doff];
            const float4 c = *(const float4*)&Tab[rowO + dout0 + doff];
            Ls[wi][doff + 0] = a.x + c.x;
            Ls[wi][doff + 1] = a.y + c.y;
            Ls[wi][doff + 2] = a.z + c.z;
            Ls[wi][doff + 3] = a.w + c.w;
        }
    }
    __syncthreads();
    const size_t obase = (size_t)b * (CC * HH * WW) + (size_t)dout0 * WW + w0;
    #pragma unroll
    for (int i = 0; i < 16; i++) {
        int flat = tid + i * 256;
        int dr = flat >> 6, wj = flat & 63;
        if (wj < wlim) out[obase + (size_t)dr * WW + wj] = Ls[wj][dr];
    }
}

// ---------------- K6: finalize loss scalar ----------------
__global__ void k_finish(const float* __restrict__ lossAcc, float* __restrict__ out) {
    if (threadIdx.x == 0)
        out[58982400] = lossAcc[0] * (0.25f / 29491200.0f);
}

extern "C" void kernel_launch(void* const* d_in, const int* in_sizes, int n_in,
                              void* d_out, int out_size, void* d_ws, size_t ws_size,
                              hipStream_t stream) {
    const float* z      = (const float*)d_in[0];
    const float* w_down = (const float*)d_in[1];
    const float* w_up   = (const float*)d_in[2];
    const float* emb    = (const float*)d_in[3];
    float* out = (float*)d_out;

    float* ws    = (float*)d_ws;
    float* Y     = ws + Y_OFF;
    float* Tab   = ws + Y_OFF;        // overlays Y after k_dist2 (last Y reader)
    float* ET    = ws + ET_OFF;
    float* norms = ws + NORM_OFF;
    unsigned long long* best = (unsigned long long*)(ws + BEST_OFF);
    float* lossA = ws + LOSS_OFF;
    float* znorm = ws + ZN_OFF;

    hipMemsetAsync(best, 0xFF, (size_t)GG * NV * sizeof(unsigned long long), stream);
    hipMemsetAsync(lossA, 0, sizeof(float), stream);

    dim3 gdown(6, 300);
    k_gemm_down<<<gdown, 256, 0, stream>>>(z, w_down, Y);

    k_transpose<<<(GG * KK * DD + 255) / 256, 256, 0, stream>>>(emb, ET);
    k_norms<<<GG * KK, 64, 0, stream>>>(ET, norms);

    dim3 gdist(1200, GG);
    k_dist2<<<gdist, 256, 0, stream>>>(Y, ET, norms, best, znorm);

    k_sumloss<<<225, 256, 0, stream>>>(best, znorm, lossA);

    dim3 gtab(16, 12, 8);
    k_table<<<gtab, 256, 0, stream>>>(ET, w_up, Tab);

    dim3 gsc(24, 19, 32);
    k_scatter<<<gsc, 256, 0, stream>>>(Tab, best, out);

    k_finish<<<1, 64, 0, stream>>>(lossA, out);
}

// Round 10
// 2000.814 us; speedup vs baseline: 1.0536x; 1.0536x over previous
//
#include <hip/hip_runtime.h>

#define BB 32
#define CC 128
#define HH 12
#define WW 1200
#define DIN 1536
#define FIXD 768
#define OVL 4
#define GG 6
#define DD 512
#define KK 1024
#define TT 300
#define NV 9600        /* B*T vectors per group */
#define MROWS 38400    /* B*W */

// workspace layout (float offsets)
#define Y_OFF     0          /* 29,491,200 floats; Tab overlays this after rescore/fallback */
#define ET_OFF    29491200
#define NORM_OFF  32636928
#define BEST_OFF  32643072   /* 57600 uint64 */
#define LOSS_OFF  32758272
#define ZN_OFF    32758336   /* 57600 */
#define UMIN_OFF  32815936   /* 57600 u32 */
#define CNT_OFF   32873536   /* 57600 u32 */
#define MAXN_OFF  32931136   /* 64 (6 used) */
#define LIST_OFF  32931200   /* 57600*64 u32 */
#define YBF_OFF   36617600   /* 29,491,200 ushort */
#define EBF_OFF   51363200   /* 3,145,728 ushort */

// LDS column swizzle for B-side fp32 tiles (placement-only)
#define BSWZ(c) ((c) + 4 * ((c) >> 5))

typedef __attribute__((ext_vector_type(8))) short bf16x8;
typedef __attribute__((ext_vector_type(4))) float f32x4;

static __device__ inline unsigned short f2bf(float x) {
    unsigned u = __float_as_uint(x);
    unsigned r = (u + 0x7fffu + ((u >> 16) & 1u)) >> 16;
    return (unsigned short)r;
}
static __device__ inline unsigned enc32(float s) {
    unsigned u = __float_as_uint(s);
    return (u & 0x80000000u) ? ~u : (u | 0x80000000u);
}

// ---------------- K1: proj_down fp32 GEMM (R8 form; bit-exact chain) ---------
__global__ __launch_bounds__(256) void k_gemm_down(const float* __restrict__ z,
                                                   const float* __restrict__ w_down,
                                                   float* __restrict__ Y) {
    __shared__ float As[16][132];
    __shared__ float Bs[16][140];
    const int n0 = blockIdx.y * 128, f0 = blockIdx.x * 128;
    const int tid = threadIdx.x;
    const int arow = tid & 127;
    const int ak0 = tid >> 7;
    const int nA = n0 + arow;
    const int bA = nA / WW, wA = nA - bA * WW;
    const size_t zbase = (size_t)bA * (CC * HH * WW) + wA;
    const int bcol = tid >> 1, bq = tid & 1;
    const int bsc = BSWZ(bcol);
    const int trow = tid >> 4, tcol = tid & 15;
    const int bread = tcol * 8 + 4 * (tcol >> 2);
    float acc[8][8] = {};
    for (int kt = 0; kt < DIN; kt += 16) {
        #pragma unroll
        for (int i = 0; i < 8; i++) {
            const int kk = ak0 + i * 2;
            As[kk][arow] = z[zbase + (size_t)(kt + kk) * WW];
        }
        #pragma unroll
        for (int i = 0; i < 2; i++) {
            const int q = bq + i * 2;
            const float4 v = *(const float4*)&w_down[(size_t)(f0 + bcol) * DIN + kt + q * 4];
            Bs[q * 4 + 0][bsc] = v.x;
            Bs[q * 4 + 1][bsc] = v.y;
            Bs[q * 4 + 2][bsc] = v.z;
            Bs[q * 4 + 3][bsc] = v.w;
        }
        __syncthreads();
        #pragma unroll
        for (int k = 0; k < 16; k++) {
            float av[8], bv[8];
            *(float4*)&av[0] = *(const float4*)&As[k][trow * 8];
            *(float4*)&av[4] = *(const float4*)&As[k][trow * 8 + 4];
            *(float4*)&bv[0] = *(const float4*)&Bs[k][bread];
            *(float4*)&bv[4] = *(const float4*)&Bs[k][bread + 4];
            #pragma unroll
            for (int i = 0; i < 8; i++)
                #pragma unroll
                for (int j = 0; j < 8; j++)
                    acc[i][j] = fmaf(av[i], bv[j], acc[i][j]);
        }
        __syncthreads();
    }
    #pragma unroll
    for (int i = 0; i < 8; i++) {
        float4 o0, o1;
        o0.x = acc[i][0]; o0.y = acc[i][1]; o0.z = acc[i][2]; o0.w = acc[i][3];
        o1.x = acc[i][4]; o1.y = acc[i][5]; o1.z = acc[i][6]; o1.w = acc[i][7];
        float* yr = &Y[(size_t)(n0 + trow * 8 + i) * FIXD + f0 + tcol * 8];
        *(float4*)yr = o0;
        *(float4*)(yr + 4) = o1;
    }
}

// ---------------- K2: transpose codebook emb(g,d,k) -> ET(g,k,d) -------------
__global__ __launch_bounds__(256) void k_transpose(const float* __restrict__ emb,
                                                   float* __restrict__ ET) {
    int i = blockIdx.x * 256 + threadIdx.x;
    if (i >= GG * KK * DD) return;
    int d = i & 511;
    int rem = i >> 9;
    int k = rem & 1023;
    int g = rem >> 10;
    ET[i] = emb[((g * DD + d) << 10) + k];
}

// ---------------- K2b: per-code norms (fp64) + per-group max norm ------------
__global__ __launch_bounds__(64) void k_norms(const float* __restrict__ ET,
                                              float* __restrict__ norms,
                                              unsigned* __restrict__ maxnU) {
    const int code = blockIdx.x;
    const int lane = threadIdx.x;
    const float* row = ET + code * DD;
    double s = 0.0;
    #pragma unroll
    for (int r = 0; r < 8; r++) {
        float v = row[lane + r * 64];
        s += (double)v * (double)v;
    }
    #pragma unroll
    for (int off = 32; off; off >>= 1) s += __shfl_down(s, off);
    if (lane == 0) {
        const float nf = (float)s;
        norms[code] = nf;
        atomicMax(&maxnU[code >> 10], __float_as_uint(nf));
    }
}

// ---------------- K3a: Y -> Ybf[g][v][d] bf16, plus znorm --------------------
__global__ __launch_bounds__(256) void k_ysplit(const float* __restrict__ Y,
                                                unsigned short* __restrict__ Ybf,
                                                float* __restrict__ znorm) {
    const int gv = blockIdx.x * 4 + (threadIdx.x >> 6);   // 0..57599
    const int lane = threadIdx.x & 63;
    const int g = gv / NV, r = gv - g * NV;
    const int b = r / TT, t = r - b * TT;
    const int d0 = lane * 8;
    const int p = g * DD + d0;                 // 8-run never straddles (split at d=256)
    const int sg = p / FIXD, f = p - sg * FIXD;
    const float* yb = &Y[(size_t)((b * WW + t * OVL + sg) * FIXD + f)];
    const float4 y0 = *(const float4*)yb;
    const float4 y1 = *(const float4*)(yb + 4);
    unsigned short h[8];
    h[0] = f2bf(y0.x); h[1] = f2bf(y0.y); h[2] = f2bf(y0.z); h[3] = f2bf(y0.w);
    h[4] = f2bf(y1.x); h[5] = f2bf(y1.y); h[6] = f2bf(y1.z); h[7] = f2bf(y1.w);
    *(uint4*)&Ybf[(size_t)gv * DD + d0] = *(uint4*)&h[0];
    float s = 0.f;
    s = fmaf(y0.x, y0.x, s); s = fmaf(y0.y, y0.y, s);
    s = fmaf(y0.z, y0.z, s); s = fmaf(y0.w, y0.w, s);
    s = fmaf(y1.x, y1.x, s); s = fmaf(y1.y, y1.y, s);
    s = fmaf(y1.z, y1.z, s); s = fmaf(y1.w, y1.w, s);
    #pragma unroll
    for (int off = 32; off; off >>= 1) s += __shfl_down(s, off);
    if (lane == 0) znorm[gv] = s;
}

// ---------------- K3b: ET -> Ebf bf16 ----------------------------------------
__global__ __launch_bounds__(256) void k_esplit(const float* __restrict__ ET,
                                                unsigned short* __restrict__ Ebf) {
    const size_t i8 = ((size_t)blockIdx.x * 256 + threadIdx.x) * 8;  // 1536 blocks
    const float4 a = *(const float4*)&ET[i8];
    const float4 b = *(const float4*)&ET[i8 + 4];
    unsigned short h[8];
    h[0] = f2bf(a.x); h[1] = f2bf(a.y); h[2] = f2bf(a.z); h[3] = f2bf(a.w);
    h[4] = f2bf(b.x); h[5] = f2bf(b.y); h[6] = f2bf(b.z); h[7] = f2bf(b.w);
    *(uint4*)&Ebf[i8] = *(uint4*)&h[0];
}

// ---------------- K4: MFMA approx distances ----------------------------------
// PHASE 1: per-vector approx min over codes -> atomicMin(umin).
// PHASE 2: recompute (deterministic), collect codes with score <= a1 + marg.
// marg = 0.032*sqrt(znorm_v * maxnorm_g) is a rigorous (2x-cushioned) bound on
// 2*(approx-chain) score error -> chain-winner is guaranteed in the list.
template<int PHASE>
__global__ __launch_bounds__(256) void k_dist3(const unsigned short* __restrict__ Ybf,
                                               const unsigned short* __restrict__ Ebf,
                                               const float* __restrict__ norms,
                                               const float* __restrict__ znorm,
                                               const unsigned* __restrict__ maxnU,
                                               unsigned* __restrict__ umin,
                                               unsigned* __restrict__ cnt,
                                               unsigned* __restrict__ list_) {
    __shared__ unsigned short Ah[128][40], Bh[128][40];
    __shared__ float a1s[128], margs[128];
    const int vt = blockIdx.x;     // 75
    const int ct = blockIdx.y;     // 8
    const int g  = blockIdx.z;     // 6
    const int v0 = vt * 128, c0 = ct * 128;
    const int tid = threadIdx.x;
    const size_t ybase = ((size_t)g * NV + v0) * DD;
    const size_t ebase = ((size_t)g * KK + c0) * DD;
    const int srow = tid >> 1, sseg = (tid & 1) * 16;
    const int wv = tid >> 6, lane = tid & 63;
    const int wr = wv >> 1, wc = wv & 1;
    const int m0 = wr * 64, n0 = wc * 64;
    const int lr = lane & 15, lq = lane >> 4;

    if (PHASE == 2 && tid < 128) {
        const int gv = g * NV + v0 + tid;
        const unsigned u = umin[gv];
        const unsigned x = (u & 0x80000000u) ? (u & 0x7fffffffu) : ~u;
        a1s[tid] = __uint_as_float(x);
        margs[tid] = 0.032f * sqrtf(znorm[gv] * __uint_as_float(maxnU[g]));
    }

    f32x4 acc[4][4];
    #pragma unroll
    for (int i = 0; i < 4; i++)
        #pragma unroll
        for (int j = 0; j < 4; j++) acc[i][j] = (f32x4){0.f, 0.f, 0.f, 0.f};

    for (int kt = 0; kt < DD; kt += 32) {
        {
            const uint4 a0 = *(const uint4*)&Ybf[ybase + (size_t)srow * DD + kt + sseg];
            const uint4 a1 = *(const uint4*)&Ybf[ybase + (size_t)srow * DD + kt + sseg + 8];
            const uint4 b0 = *(const uint4*)&Ebf[ebase + (size_t)srow * DD + kt + sseg];
            const uint4 b1 = *(const uint4*)&Ebf[ebase + (size_t)srow * DD + kt + sseg + 8];
            *(uint4*)&Ah[srow][sseg]     = a0;
            *(uint4*)&Ah[srow][sseg + 8] = a1;
            *(uint4*)&Bh[srow][sseg]     = b0;
            *(uint4*)&Bh[srow][sseg + 8] = b1;
        }
        __syncthreads();
        bf16x8 ah[4], bh[4];
        #pragma unroll
        for (int i = 0; i < 4; i++) {
            ah[i] = *(bf16x8*)&Ah[m0 + i * 16 + lr][lq * 8];
            bh[i] = *(bf16x8*)&Bh[n0 + i * 16 + lr][lq * 8];
        }
        #pragma unroll
        for (int i = 0; i < 4; i++)
            #pragma unroll
            for (int j = 0; j < 4; j++)
                acc[i][j] = __builtin_amdgcn_mfma_f32_16x16x32_bf16(ah[i], bh[j], acc[i][j], 0, 0, 0);
        __syncthreads();
    }

    float nrmj[4];
    #pragma unroll
    for (int j = 0; j < 4; j++) nrmj[j] = norms[(g << 10) + c0 + n0 + j * 16 + lr];

    #pragma unroll
    for (int i = 0; i < 4; i++) {
        #pragma unroll
        for (int rr = 0; rr < 4; rr++) {
            const int row = m0 + i * 16 + lq * 4 + rr;
            if (PHASE == 1) {
                unsigned kb = 0xFFFFFFFFu;
                #pragma unroll
                for (int j = 0; j < 4; j++) {
                    const unsigned u = enc32(nrmj[j] - 2.0f * acc[i][j][rr]);
                    kb = (u < kb) ? u : kb;
                }
                #pragma unroll
                for (int off = 1; off < 16; off <<= 1) {
                    const unsigned o = __shfl_xor(kb, off);
                    kb = (o < kb) ? o : kb;
                }
                if (lr == 0) atomicMin(&umin[g * NV + v0 + row], kb);
            } else {
                const float thr = a1s[row] + margs[row];
                #pragma unroll
                for (int j = 0; j < 4; j++) {
                    const float sc = nrmj[j] - 2.0f * acc[i][j][rr];
                    if (sc <= thr) {
                        const int gv = g * NV + v0 + row;
                        const unsigned idx = atomicAdd(&cnt[gv], 1u);
                        if (idx < 64u)
                            list_[(size_t)gv * 64 + idx] = (unsigned)(c0 + n0 + j * 16 + lr);
                    }
                }
            }
        }
    }
}

// ---------------- K5: exact rescore of candidates (bit-identical chain) ------
__global__ __launch_bounds__(64) void k_rescore(const float* __restrict__ Y,
                                                const float* __restrict__ ET,
                                                const float* __restrict__ norms,
                                                const unsigned* __restrict__ cnt,
                                                const unsigned* __restrict__ list_,
                                                unsigned long long* __restrict__ best) {
    const int gv = blockIdx.x;
    const unsigned n = cnt[gv];
    if (n == 0u || n > 64u) return;      // n>64 -> fallback kernel
    const int lane = threadIdx.x;
    const int g = gv / NV, r = gv - g * NV;
    const int b = r / TT, t = r - b * TT;
    unsigned long long key = ~0ull;
    if (lane < (int)n) {
        const unsigned c = list_[(size_t)gv * 64 + lane];
        const float* erow = &ET[((size_t)((g << 10) + c)) * DD];
        float s = 0.f;
        for (int d4 = 0; d4 < 128; ++d4) {
            const int p = g * DD + d4 * 4;
            const int sg = p / FIXD, f = p - sg * FIXD;
            const float4 yv = *(const float4*)&Y[(size_t)((b * WW + t * OVL + sg) * FIXD + f)];
            const float4 ev = *(const float4*)&erow[d4 * 4];
            s = fmaf(yv.x, ev.x, s); s = fmaf(yv.y, ev.y, s);
            s = fmaf(yv.z, ev.z, s); s = fmaf(yv.w, ev.w, s);
        }
        const float sc = norms[(g << 10) + c] - 2.0f * s;
        key = ((unsigned long long)enc32(sc) << 32) | c;
    }
    #pragma unroll
    for (int off = 32; off; off >>= 1) {
        const unsigned long long o = __shfl_down(key, off);
        if (o < key) key = o;
    }
    if (lane == 0) best[gv] = key;
}

// ---------------- K5b: exact fallback for overflowed vectors (rare) ----------
__global__ __launch_bounds__(256) void k_fallback(const float* __restrict__ Y,
                                                  const float* __restrict__ ET,
                                                  const float* __restrict__ norms,
                                                  const unsigned* __restrict__ cnt,
                                                  unsigned long long* __restrict__ best) {
    const int gv = blockIdx.x;
    if (cnt[gv] <= 64u) return;
    __shared__ float Yv[512];
    __shared__ unsigned long long red[256];
    const int tid = threadIdx.x;
    const int g = gv / NV, r = gv - g * NV;
    const int b = r / TT, t = r - b * TT;
    if (tid < 128) {
        const int p = g * DD + tid * 4;
        const int sg = p / FIXD, f = p - sg * FIXD;
        *(float4*)&Yv[tid * 4] = *(const float4*)&Y[(size_t)((b * WW + t * OVL + sg) * FIXD + f)];
    }
    __syncthreads();
    unsigned long long kb = ~0ull;
    for (int cc = 0; cc < 4; ++cc) {
        const int c = tid + cc * 256;
        const float* erow = &ET[((size_t)((g << 10) + c)) * DD];
        float s = 0.f;
        for (int d = 0; d < 512; ++d) s = fmaf(Yv[d], erow[d], s);
        const float sc = norms[(g << 10) + c] - 2.0f * s;
        const unsigned long long key = ((unsigned long long)enc32(sc) << 32) | (unsigned)c;
        if (key < kb) kb = key;
    }
    red[tid] = kb;
    __syncthreads();
    for (int off = 128; off; off >>= 1) {
        if (tid < off) { if (red[tid + off] < red[tid]) red[tid] = red[tid + off]; }
        __syncthreads();
    }
    if (tid == 0) best[gv] = red[0];
}

// ---------------- K6: loss = sum_v (best_score_v + |z_v|^2) ------------------
__global__ __launch_bounds__(256) void k_sumloss(const unsigned long long* __restrict__ best,
                                                 const float* __restrict__ znorm,
                                                 float* __restrict__ lossAcc) {
    const int v = blockIdx.x * 256 + threadIdx.x;
    const unsigned long long key = best[v];
    const unsigned u = (unsigned)(key >> 32);
    const unsigned x = (u & 0x80000000u) ? (u & 0x7fffffffu) : ~u;
    float s = __uint_as_float(x) + znorm[v];
    __shared__ float red[256];
    red[threadIdx.x] = s;
    __syncthreads();
    for (int off = 128; off; off >>= 1) {
        if (threadIdx.x < off) red[threadIdx.x] += red[threadIdx.x + off];
        __syncthreads();
    }
    if (threadIdx.x == 0) atomicAdd(lossAcc, red[0]);
}

// ---------------- K7a: per-(segment,code) up-projection table ----------------
__constant__ int SEG_G[8]  = {0, 1, 1, 2, 3, 4, 4, 5};
__constant__ int SEG_D0[8] = {0, 0, 256, 0, 0, 0, 256, 0};
__constant__ int SEG_L[8]  = {512, 256, 256, 512, 512, 256, 256, 512};
__constant__ int SEG_F0[8] = {0, 512, 0, 256, 0, 512, 0, 256};

__global__ __launch_bounds__(256) void k_table(const float* __restrict__ ET,
                                               const float* __restrict__ w_up,
                                               float* __restrict__ Tab) {
    __shared__ float As[16][68];
    __shared__ float Bs[16][140];
    const int bm = blockIdx.x;
    const int bn = blockIdx.y;
    const int seg = blockIdx.z;
    const int g = SEG_G[seg], d0 = SEG_D0[seg], len = SEG_L[seg], fb = SEG_F0[seg];
    const int tid = threadIdx.x;
    const int k0 = bm * 64, dout0 = bn * 128;
    const int arow = tid >> 2, aq = tid & 3;
    const int rbase = (tid >> 4) << 2;
    const int cgrp = tid & 15;
    const int bread = cgrp * 8 + 4 * (cgrp >> 2);
    const float* ETg = ET + (size_t)(g << 10) * DD;
    float acc[4][8] = {};
    for (int kt = 0; kt < len; kt += 16) {
        {
            const float4 v = *(const float4*)&ETg[(size_t)(k0 + arow) * DD + d0 + kt + aq * 4];
            As[aq * 4 + 0][arow] = v.x;
            As[aq * 4 + 1][arow] = v.y;
            As[aq * 4 + 2][arow] = v.z;
            As[aq * 4 + 3][arow] = v.w;
        }
        #pragma unroll
        for (int i = 0; i < 2; i++) {
            int fl = tid + i * 256;
            int col = fl >> 2, q = fl & 3;
            const int sc = BSWZ(col);
            const float4 v = *(const float4*)&w_up[(size_t)(dout0 + col) * FIXD + fb + kt + q * 4];
            Bs[q * 4 + 0][sc] = v.x;
            Bs[q * 4 + 1][sc] = v.y;
            Bs[q * 4 + 2][sc] = v.z;
            Bs[q * 4 + 3][sc] = v.w;
        }
        __syncthreads();
        #pragma unroll
        for (int k = 0; k < 16; k++) {
            const float4 a  = *(const float4*)&As[k][rbase];
            const float4 ba = *(const float4*)&Bs[k][bread];
            const float4 bb = *(const float4*)&Bs[k][bread + 4];
            const float av[4] = {a.x, a.y, a.z, a.w};
            const float bv[8] = {ba.x, ba.y, ba.z, ba.w, bb.x, bb.y, bb.z, bb.w};
            #pragma unroll
            for (int i = 0; i < 4; i++)
                #pragma unroll
                for (int j = 0; j < 8; j++)
                    acc[i][j] = fmaf(av[i], bv[j], acc[i][j]);
        }
        __syncthreads();
    }
    #pragma unroll
    for (int i = 0; i < 4; i++) {
        float4 o0, o1;
        o0.x = acc[i][0]; o0.y = acc[i][1]; o0.z = acc[i][2]; o0.w = acc[i][3];
        o1.x = acc[i][4]; o1.y = acc[i][5]; o1.z = acc[i][6]; o1.w = acc[i][7];
        float* tr = &Tab[(size_t)((seg << 10) + k0 + rbase + i) * DIN + dout0 + cgrp * 8];
        *(float4*)tr = o0;
        *(float4*)(tr + 4) = o1;
    }
}

// ---------------- K7b: gather-add scatter to output --------------------------
__global__ __launch_bounds__(256) void k_scatter(const float* __restrict__ Tab,
                                                 const unsigned long long* __restrict__ best,
                                                 float* __restrict__ out) {
    __shared__ float Ls[64][65];
    const int dt = blockIdx.x;
    const int wt = blockIdx.y;
    const int b  = blockIdx.z;
    const int dout0 = dt * 64, w0 = wt * 64;
    const int wlim = (WW - w0 < 64) ? (WW - w0) : 64;
    const int tid = threadIdx.x;
    const int wi = tid >> 2, q = tid & 3;

    if (wi < wlim) {
        const int w = w0 + wi;
        const int s = w & 3;
        const int t = w >> 2;
        const int gEt[4] = {0, 1, 3, 4};
        const int gOt[4] = {1, 2, 4, 5};
        int ce = (int)(unsigned)best[gEt[s] * NV + b * TT + t];
        int co = (int)(unsigned)best[gOt[s] * NV + b * TT + t];
        size_t rowE = (size_t)(((2 * s) << 10) + ce) * DIN;
        size_t rowO = (size_t)(((2 * s + 1) << 10) + co) * DIN;
        #pragma unroll
        for (int rep = 0; rep < 4; rep++) {
            const int doff = rep * 16 + q * 4;
            const float4 a = *(const float4*)&Tab[rowE + dout0 + doff];
            const float4 c = *(const float4*)&Tab[rowO + dout0 + doff];
            Ls[wi][doff + 0] = a.x + c.x;
            Ls[wi][doff + 1] = a.y + c.y;
            Ls[wi][doff + 2] = a.z + c.z;
            Ls[wi][doff + 3] = a.w + c.w;
        }
    }
    __syncthreads();
    const size_t obase = (size_t)b * (CC * HH * WW) + (size_t)dout0 * WW + w0;
    #pragma unroll
    for (int i = 0; i < 16; i++) {
        int flat = tid + i * 256;
        int dr = flat >> 6, wj = flat & 63;
        if (wj < wlim) out[obase + (size_t)dr * WW + wj] = Ls[wj][dr];
    }
}

// ---------------- K8: finalize loss scalar -----------------------------------
__global__ void k_finish(const float* __restrict__ lossAcc, float* __restrict__ out) {
    if (threadIdx.x == 0)
        out[58982400] = lossAcc[0] * (0.25f / 29491200.0f);
}

extern "C" void kernel_launch(void* const* d_in, const int* in_sizes, int n_in,
                              void* d_out, int out_size, void* d_ws, size_t ws_size,
                              hipStream_t stream) {
    const float* z      = (const float*)d_in[0];
    const float* w_down = (const float*)d_in[1];
    const float* w_up   = (const float*)d_in[2];
    const float* emb    = (const float*)d_in[3];
    float* out = (float*)d_out;

    float* ws    = (float*)d_ws;
    float* Y     = ws + Y_OFF;
    float* Tab   = ws + Y_OFF;        // overlays Y after rescore/fallback
    float* ET    = ws + ET_OFF;
    float* norms = ws + NORM_OFF;
    unsigned long long* best = (unsigned long long*)(ws + BEST_OFF);
    float* lossA = ws + LOSS_OFF;
    float* znorm = ws + ZN_OFF;
    unsigned* umin  = (unsigned*)(ws + UMIN_OFF);
    unsigned* cnt   = (unsigned*)(ws + CNT_OFF);
    unsigned* maxnU = (unsigned*)(ws + MAXN_OFF);
    unsigned* list_ = (unsigned*)(ws + LIST_OFF);
    unsigned short* Ybf = (unsigned short*)(ws + YBF_OFF);
    unsigned short* Ebf = (unsigned short*)(ws + EBF_OFF);

    hipMemsetAsync(best, 0xFF, (size_t)GG * NV * sizeof(unsigned long long), stream);
    hipMemsetAsync(umin, 0xFF, (size_t)GG * NV * sizeof(unsigned), stream);
    hipMemsetAsync(cnt, 0, (size_t)GG * NV * sizeof(unsigned), stream);
    hipMemsetAsync(maxnU, 0, 64, stream);
    hipMemsetAsync(lossA, 0, sizeof(float), stream);

    dim3 gdown(6, 300);
    k_gemm_down<<<gdown, 256, 0, stream>>>(z, w_down, Y);

    k_transpose<<<(GG * KK * DD + 255) / 256, 256, 0, stream>>>(emb, ET);
    k_norms<<<GG * KK, 64, 0, stream>>>(ET, norms, maxnU);

    k_ysplit<<<GG * NV / 4, 256, 0, stream>>>(Y, Ybf, znorm);
    k_esplit<<<GG * KK * DD / (256 * 8), 256, 0, stream>>>(ET, Ebf);

    dim3 gdist(75, 8, GG);
    k_dist3<1><<<gdist, 256, 0, stream>>>(Ybf, Ebf, norms, znorm, maxnU, umin, cnt, list_);
    k_dist3<2><<<gdist, 256, 0, stream>>>(Ybf, Ebf, norms, znorm, maxnU, umin, cnt, list_);

    k_rescore<<<GG * NV, 64, 0, stream>>>(Y, ET, norms, cnt, list_, best);
    k_fallback<<<GG * NV, 256, 0, stream>>>(Y, ET, norms, cnt, best);

    k_sumloss<<<225, 256, 0, stream>>>(best, znorm, lossA);

    dim3 gtab(16, 12, 8);
    k_table<<<gtab, 256, 0, stream>>>(ET, w_up, Tab);

    dim3 gsc(24, 19, 32);
    k_scatter<<<gsc, 256, 0, stream>>>(Tab, best, out);

    k_finish<<<1, 64, 0, stream>>>(lossA, out);
}

// Round 11
// 1995.158 us; speedup vs baseline: 1.0566x; 1.0028x over previous
//
#include <hip/hip_runtime.h>

#define BB 32
#define CC 128
#define HH 12
#define WW 1200
#define DIN 1536
#define FIXD 768
#define OVL 4
#define GG 6
#define DD 512
#define KK 1024
#define TT 300
#define NV 9600        /* B*T vectors per group */
#define MROWS 38400    /* B*W */

// workspace layout (float offsets)
#define Y_OFF     0          /* 29,491,200 floats; Tab overlays this after rescore/fallback */
#define ET_OFF    29491200
#define NORM_OFF  32636928
#define BEST_OFF  32643072   /* 57600 uint64 */
#define LOSS_OFF  32758272
#define ZN_OFF    32758336   /* 57600 */
#define UMIN_OFF  32815936   /* 57600 u32 */
#define CNT_OFF   32873536   /* 57600 u32 */
#define MAXN_OFF  32931136   /* 64 (6 used) */
#define LIST_OFF  32931200   /* 57600*64 u32 */
#define YBF_OFF   36617600   /* 29,491,200 ushort */
#define EBF_OFF   51363200   /* 3,145,728 ushort */

// LDS column swizzle for 128-wide B-side fp32 tiles (placement-only)
#define BSWZ(c) ((c) + 4 * ((c) >> 5))

typedef __attribute__((ext_vector_type(8))) short bf16x8;
typedef __attribute__((ext_vector_type(4))) float f32x4;

static __device__ inline unsigned short f2bf(float x) {
    unsigned u = __float_as_uint(x);
    unsigned r = (u + 0x7fffu + ((u >> 16) & 1u)) >> 16;
    return (unsigned short)r;
}
static __device__ inline unsigned enc32(float s) {
    unsigned u = __float_as_uint(s);
    return (u & 0x80000000u) ? ~u : (u | 0x80000000u);
}

// ---------------- K1: proj_down fp32 GEMM, 128x256 tile, 8x16/thread ---------
// Y[n][f] = sum_k z[b*1843200 + k*1200 + w] * w_down[f*1536+k];  n = b*1200+w
// Per-output accumulation strictly k-sequential (kt outer 16-step, k inner
// 0..15) -> Y bit-identical to R3..R10 (argmin-critical: do NOT change order).
// 8x16 register tile: 128 FMA : 6 ds_read_b128 per k (was 64:4) -- raises
// FMA/LDS-read ratio 33% to relieve the shared LDS pipe.
// B swizzle: col' = col + 4*(col>>4), pitch 320 -> the 16-lane x 4-b128 column
// reads land on all 32 banks exactly 2-way (free per m136).
__global__ __launch_bounds__(256, 3) void k_gemm_down(const float* __restrict__ z,
                                                      const float* __restrict__ w_down,
                                                      float* __restrict__ Y) {
    __shared__ float As[16][132];
    __shared__ float Bs[16][320];
    const int n0 = blockIdx.y * 128, f0 = blockIdx.x * 256;
    const int tid = threadIdx.x;
    // A staging: row fixed per thread (128 rows), 8 k-slots (k = ak0 + 2*i)
    const int arow = tid & 127;
    const int ak0 = tid >> 7;           // 0..1
    const int nA = n0 + arow;
    const int bA = nA / WW, wA = nA - bA * WW;
    const size_t zbase = (size_t)bA * (CC * HH * WW) + wA;
    // B staging: col = tid (256 cols), 4 float4 (full 16-k column)
    const int bcol = tid;
    const int bsc = bcol + 4 * (bcol >> 4);
    // compute thread grid 16x16: trow -> 8 rows, tcol -> 16 cols
    const int trow = tid >> 4, tcol = tid & 15;
    const int bread = tcol * 20;        // swizzled base of col group (16 cols)
    float acc[8][16] = {};
    for (int kt = 0; kt < DIN; kt += 16) {
        #pragma unroll
        for (int i = 0; i < 8; i++) {
            const int kk = ak0 + i * 2;
            As[kk][arow] = z[zbase + (size_t)(kt + kk) * WW];
        }
        #pragma unroll
        for (int q = 0; q < 4; q++) {
            const float4 v = *(const float4*)&w_down[(size_t)(f0 + bcol) * DIN + kt + q * 4];
            Bs[q * 4 + 0][bsc] = v.x;
            Bs[q * 4 + 1][bsc] = v.y;
            Bs[q * 4 + 2][bsc] = v.z;
            Bs[q * 4 + 3][bsc] = v.w;
        }
        __syncthreads();
        #pragma unroll
        for (int k = 0; k < 16; k++) {
            float av[8], bv[16];
            *(float4*)&av[0] = *(const float4*)&As[k][trow * 8];
            *(float4*)&av[4] = *(const float4*)&As[k][trow * 8 + 4];
            *(float4*)&bv[0]  = *(const float4*)&Bs[k][bread];
            *(float4*)&bv[4]  = *(const float4*)&Bs[k][bread + 4];
            *(float4*)&bv[8]  = *(const float4*)&Bs[k][bread + 8];
            *(float4*)&bv[12] = *(const float4*)&Bs[k][bread + 12];
            #pragma unroll
            for (int i = 0; i < 8; i++)
                #pragma unroll
                for (int j = 0; j < 16; j++)
                    acc[i][j] = fmaf(av[i], bv[j], acc[i][j]);
        }
        __syncthreads();
    }
    #pragma unroll
    for (int i = 0; i < 8; i++) {
        float* yr = &Y[(size_t)(n0 + trow * 8 + i) * FIXD + f0 + tcol * 16];
        #pragma unroll
        for (int q = 0; q < 4; q++) {
            float4 o;
            o.x = acc[i][q * 4 + 0]; o.y = acc[i][q * 4 + 1];
            o.z = acc[i][q * 4 + 2]; o.w = acc[i][q * 4 + 3];
            *(float4*)(yr + q * 4) = o;
        }
    }
}

// ---------------- K2: transpose codebook emb(g,d,k) -> ET(g,k,d) -------------
__global__ __launch_bounds__(256) void k_transpose(const float* __restrict__ emb,
                                                   float* __restrict__ ET) {
    int i = blockIdx.x * 256 + threadIdx.x;
    if (i >= GG * KK * DD) return;
    int d = i & 511;
    int rem = i >> 9;
    int k = rem & 1023;
    int g = rem >> 10;
    ET[i] = emb[((g * DD + d) << 10) + k];
}

// ---------------- K2b: per-code norms (fp64) + per-group max norm ------------
__global__ __launch_bounds__(64) void k_norms(const float* __restrict__ ET,
                                              float* __restrict__ norms,
                                              unsigned* __restrict__ maxnU) {
    const int code = blockIdx.x;
    const int lane = threadIdx.x;
    const float* row = ET + code * DD;
    double s = 0.0;
    #pragma unroll
    for (int r = 0; r < 8; r++) {
        float v = row[lane + r * 64];
        s += (double)v * (double)v;
    }
    #pragma unroll
    for (int off = 32; off; off >>= 1) s += __shfl_down(s, off);
    if (lane == 0) {
        const float nf = (float)s;
        norms[code] = nf;
        atomicMax(&maxnU[code >> 10], __float_as_uint(nf));
    }
}

// ---------------- K3a: Y -> Ybf[g][v][d] bf16, plus znorm --------------------
__global__ __launch_bounds__(256) void k_ysplit(const float* __restrict__ Y,
                                                unsigned short* __restrict__ Ybf,
                                                float* __restrict__ znorm) {
    const int gv = blockIdx.x * 4 + (threadIdx.x >> 6);   // 0..57599
    const int lane = threadIdx.x & 63;
    const int g = gv / NV, r = gv - g * NV;
    const int b = r / TT, t = r - b * TT;
    const int d0 = lane * 8;
    const int p = g * DD + d0;                 // 8-run never straddles (split at d=256)
    const int sg = p / FIXD, f = p - sg * FIXD;
    const float* yb = &Y[(size_t)((b * WW + t * OVL + sg) * FIXD + f)];
    const float4 y0 = *(const float4*)yb;
    const float4 y1 = *(const float4*)(yb + 4);
    unsigned short h[8];
    h[0] = f2bf(y0.x); h[1] = f2bf(y0.y); h[2] = f2bf(y0.z); h[3] = f2bf(y0.w);
    h[4] = f2bf(y1.x); h[5] = f2bf(y1.y); h[6] = f2bf(y1.z); h[7] = f2bf(y1.w);
    *(uint4*)&Ybf[(size_t)gv * DD + d0] = *(uint4*)&h[0];
    float s = 0.f;
    s = fmaf(y0.x, y0.x, s); s = fmaf(y0.y, y0.y, s);
    s = fmaf(y0.z, y0.z, s); s = fmaf(y0.w, y0.w, s);
    s = fmaf(y1.x, y1.x, s); s = fmaf(y1.y, y1.y, s);
    s = fmaf(y1.z, y1.z, s); s = fmaf(y1.w, y1.w, s);
    #pragma unroll
    for (int off = 32; off; off >>= 1) s += __shfl_down(s, off);
    if (lane == 0) znorm[gv] = s;
}

// ---------------- K3b: ET -> Ebf bf16 ----------------------------------------
__global__ __launch_bounds__(256) void k_esplit(const float* __restrict__ ET,
                                                unsigned short* __restrict__ Ebf) {
    const size_t i8 = ((size_t)blockIdx.x * 256 + threadIdx.x) * 8;  // 1536 blocks
    const float4 a = *(const float4*)&ET[i8];
    const float4 b = *(const float4*)&ET[i8 + 4];
    unsigned short h[8];
    h[0] = f2bf(a.x); h[1] = f2bf(a.y); h[2] = f2bf(a.z); h[3] = f2bf(a.w);
    h[4] = f2bf(b.x); h[5] = f2bf(b.y); h[6] = f2bf(b.z); h[7] = f2bf(b.w);
    *(uint4*)&Ebf[i8] = *(uint4*)&h[0];
}

// ---------------- K4: MFMA approx distances ----------------------------------
// PHASE 1: per-vector approx min over codes -> atomicMin(umin).
// PHASE 2: recompute (deterministic), collect codes with score <= a1 + marg.
// marg = 0.032*sqrt(znorm_v * maxnorm_g) is a rigorous (2x-cushioned) bound on
// 2*(approx-chain) score error -> chain-winner is guaranteed in the list.
// Grid (ct=8 fastest, vt, g): consecutive blocks share the vt Y-slab (L2).
template<int PHASE>
__global__ __launch_bounds__(256) void k_dist3(const unsigned short* __restrict__ Ybf,
                                               const unsigned short* __restrict__ Ebf,
                                               const float* __restrict__ norms,
                                               const float* __restrict__ znorm,
                                               const unsigned* __restrict__ maxnU,
                                               unsigned* __restrict__ umin,
                                               unsigned* __restrict__ cnt,
                                               unsigned* __restrict__ list_) {
    __shared__ unsigned short Ah[128][40], Bh[128][40];
    __shared__ float a1s[128], margs[128];
    const int ct = blockIdx.x;     // 8 (fastest -> Y-slab L2 reuse)
    const int vt = blockIdx.y;     // 75
    const int g  = blockIdx.z;     // 6
    const int v0 = vt * 128, c0 = ct * 128;
    const int tid = threadIdx.x;
    const size_t ybase = ((size_t)g * NV + v0) * DD;
    const size_t ebase = ((size_t)g * KK + c0) * DD;
    const int srow = tid >> 1, sseg = (tid & 1) * 16;
    const int wv = tid >> 6, lane = tid & 63;
    const int wr = wv >> 1, wc = wv & 1;
    const int m0 = wr * 64, n0 = wc * 64;
    const int lr = lane & 15, lq = lane >> 4;

    if (PHASE == 2 && tid < 128) {
        const int gv = g * NV + v0 + tid;
        const unsigned u = umin[gv];
        const unsigned x = (u & 0x80000000u) ? (u & 0x7fffffffu) : ~u;
        a1s[tid] = __uint_as_float(x);
        margs[tid] = 0.032f * sqrtf(znorm[gv] * __uint_as_float(maxnU[g]));
    }

    f32x4 acc[4][4];
    #pragma unroll
    for (int i = 0; i < 4; i++)
        #pragma unroll
        for (int j = 0; j < 4; j++) acc[i][j] = (f32x4){0.f, 0.f, 0.f, 0.f};

    for (int kt = 0; kt < DD; kt += 32) {
        {
            const uint4 a0 = *(const uint4*)&Ybf[ybase + (size_t)srow * DD + kt + sseg];
            const uint4 a1 = *(const uint4*)&Ybf[ybase + (size_t)srow * DD + kt + sseg + 8];
            const uint4 b0 = *(const uint4*)&Ebf[ebase + (size_t)srow * DD + kt + sseg];
            const uint4 b1 = *(const uint4*)&Ebf[ebase + (size_t)srow * DD + kt + sseg + 8];
            *(uint4*)&Ah[srow][sseg]     = a0;
            *(uint4*)&Ah[srow][sseg + 8] = a1;
            *(uint4*)&Bh[srow][sseg]     = b0;
            *(uint4*)&Bh[srow][sseg + 8] = b1;
        }
        __syncthreads();
        bf16x8 ah[4], bh[4];
        #pragma unroll
        for (int i = 0; i < 4; i++) {
            ah[i] = *(bf16x8*)&Ah[m0 + i * 16 + lr][lq * 8];
            bh[i] = *(bf16x8*)&Bh[n0 + i * 16 + lr][lq * 8];
        }
        #pragma unroll
        for (int i = 0; i < 4; i++)
            #pragma unroll
            for (int j = 0; j < 4; j++)
                acc[i][j] = __builtin_amdgcn_mfma_f32_16x16x32_bf16(ah[i], bh[j], acc[i][j], 0, 0, 0);
        __syncthreads();
    }

    float nrmj[4];
    #pragma unroll
    for (int j = 0; j < 4; j++) nrmj[j] = norms[(g << 10) + c0 + n0 + j * 16 + lr];

    #pragma unroll
    for (int i = 0; i < 4; i++) {
        #pragma unroll
        for (int rr = 0; rr < 4; rr++) {
            const int row = m0 + i * 16 + lq * 4 + rr;
            if (PHASE == 1) {
                unsigned kb = 0xFFFFFFFFu;
                #pragma unroll
                for (int j = 0; j < 4; j++) {
                    const unsigned u = enc32(nrmj[j] - 2.0f * acc[i][j][rr]);
                    kb = (u < kb) ? u : kb;
                }
                #pragma unroll
                for (int off = 1; off < 16; off <<= 1) {
                    const unsigned o = __shfl_xor(kb, off);
                    kb = (o < kb) ? o : kb;
                }
                if (lr == 0) atomicMin(&umin[g * NV + v0 + row], kb);
            } else {
                const float thr = a1s[row] + margs[row];
                #pragma unroll
                for (int j = 0; j < 4; j++) {
                    const float sc = nrmj[j] - 2.0f * acc[i][j][rr];
                    if (sc <= thr) {
                        const int gv = g * NV + v0 + row;
                        const unsigned idx = atomicAdd(&cnt[gv], 1u);
                        if (idx < 64u)
                            list_[(size_t)gv * 64 + idx] = (unsigned)(c0 + n0 + j * 16 + lr);
                    }
                }
            }
        }
    }
}

// ---------------- K5: exact rescore of candidates (bit-identical chain) ------
__global__ __launch_bounds__(64) void k_rescore(const float* __restrict__ Y,
                                                const float* __restrict__ ET,
                                                const float* __restrict__ norms,
                                                const unsigned* __restrict__ cnt,
                                                const unsigned* __restrict__ list_,
                                                unsigned long long* __restrict__ best) {
    const int gv = blockIdx.x;
    const unsigned n = cnt[gv];
    if (n == 0u || n > 64u) return;      // n>64 -> fallback kernel
    const int lane = threadIdx.x;
    const int g = gv / NV, r = gv - g * NV;
    const int b = r / TT, t = r - b * TT;
    unsigned long long key = ~0ull;
    if (lane < (int)n) {
        const unsigned c = list_[(size_t)gv * 64 + lane];
        const float* erow = &ET[((size_t)((g << 10) + c)) * DD];
        float s = 0.f;
        for (int d4 = 0; d4 < 128; ++d4) {
            const int p = g * DD + d4 * 4;
            const int sg = p / FIXD, f = p - sg * FIXD;
            const float4 yv = *(const float4*)&Y[(size_t)((b * WW + t * OVL + sg) * FIXD + f)];
            const float4 ev = *(const float4*)&erow[d4 * 4];
            s = fmaf(yv.x, ev.x, s); s = fmaf(yv.y, ev.y, s);
            s = fmaf(yv.z, ev.z, s); s = fmaf(yv.w, ev.w, s);
        }
        const float sc = norms[(g << 10) + c] - 2.0f * s;
        key = ((unsigned long long)enc32(sc) << 32) | c;
    }
    #pragma unroll
    for (int off = 32; off; off >>= 1) {
        const unsigned long long o = __shfl_down(key, off);
        if (o < key) key = o;
    }
    if (lane == 0) best[gv] = key;
}

// ---------------- K5b: exact fallback for overflowed vectors (rare) ----------
__global__ __launch_bounds__(256) void k_fallback(const float* __restrict__ Y,
                                                  const float* __restrict__ ET,
                                                  const float* __restrict__ norms,
                                                  const unsigned* __restrict__ cnt,
                                                  unsigned long long* __restrict__ best) {
    const int gv = blockIdx.x;
    if (cnt[gv] <= 64u) return;
    __shared__ float Yv[512];
    __shared__ unsigned long long red[256];
    const int tid = threadIdx.x;
    const int g = gv / NV, r = gv - g * NV;
    const int b = r / TT, t = r - b * TT;
    if (tid < 128) {
        const int p = g * DD + tid * 4;
        const int sg = p / FIXD, f = p - sg * FIXD;
        *(float4*)&Yv[tid * 4] = *(const float4*)&Y[(size_t)((b * WW + t * OVL + sg) * FIXD + f)];
    }
    __syncthreads();
    unsigned long long kb = ~0ull;
    for (int cc = 0; cc < 4; ++cc) {
        const int c = tid + cc * 256;
        const float* erow = &ET[((size_t)((g << 10) + c)) * DD];
        float s = 0.f;
        for (int d = 0; d < 512; ++d) s = fmaf(Yv[d], erow[d], s);
        const float sc = norms[(g << 10) + c] - 2.0f * s;
        const unsigned long long key = ((unsigned long long)enc32(sc) << 32) | (unsigned)c;
        if (key < kb) kb = key;
    }
    red[tid] = kb;
    __syncthreads();
    for (int off = 128; off; off >>= 1) {
        if (tid < off) { if (red[tid + off] < red[tid]) red[tid] = red[tid + off]; }
        __syncthreads();
    }
    if (tid == 0) best[gv] = red[0];
}

// ---------------- K6: loss = sum_v (best_score_v + |z_v|^2) ------------------
__global__ __launch_bounds__(256) void k_sumloss(const unsigned long long* __restrict__ best,
                                                 const float* __restrict__ znorm,
                                                 float* __restrict__ lossAcc) {
    const int v = blockIdx.x * 256 + threadIdx.x;
    const unsigned long long key = best[v];
    const unsigned u = (unsigned)(key >> 32);
    const unsigned x = (u & 0x80000000u) ? (u & 0x7fffffffu) : ~u;
    float s = __uint_as_float(x) + znorm[v];
    __shared__ float red[256];
    red[threadIdx.x] = s;
    __syncthreads();
    for (int off = 128; off; off >>= 1) {
        if (threadIdx.x < off) red[threadIdx.x] += red[threadIdx.x + off];
        __syncthreads();
    }
    if (threadIdx.x == 0) atomicAdd(lossAcc, red[0]);
}

// ---------------- K7a: per-(segment,code) up-projection table ----------------
__constant__ int SEG_G[8]  = {0, 1, 1, 2, 3, 4, 4, 5};
__constant__ int SEG_D0[8] = {0, 0, 256, 0, 0, 0, 256, 0};
__constant__ int SEG_L[8]  = {512, 256, 256, 512, 512, 256, 256, 512};
__constant__ int SEG_F0[8] = {0, 512, 0, 256, 0, 512, 0, 256};

__global__ __launch_bounds__(256) void k_table(const float* __restrict__ ET,
                                               const float* __restrict__ w_up,
                                               float* __restrict__ Tab) {
    __shared__ float As[16][68];
    __shared__ float Bs[16][140];
    const int bm = blockIdx.x;
    const int bn = blockIdx.y;
    const int seg = blockIdx.z;
    const int g = SEG_G[seg], d0 = SEG_D0[seg], len = SEG_L[seg], fb = SEG_F0[seg];
    const int tid = threadIdx.x;
    const int k0 = bm * 64, dout0 = bn * 128;
    const int arow = tid >> 2, aq = tid & 3;
    const int rbase = (tid >> 4) << 2;
    const int cgrp = tid & 15;
    const int bread = cgrp * 8 + 4 * (cgrp >> 2);
    const float* ETg = ET + (size_t)(g << 10) * DD;
    float acc[4][8] = {};
    for (int kt = 0; kt < len; kt += 16) {
        {
            const float4 v = *(const float4*)&ETg[(size_t)(k0 + arow) * DD + d0 + kt + aq * 4];
            As[aq * 4 + 0][arow] = v.x;
            As[aq * 4 + 1][arow] = v.y;
            As[aq * 4 + 2][arow] = v.z;
            As[aq * 4 + 3][arow] = v.w;
        }
        #pragma unroll
        for (int i = 0; i < 2; i++) {
            int fl = tid + i * 256;
            int col = fl >> 2, q = fl & 3;
            const int sc = BSWZ(col);
            const float4 v = *(const float4*)&w_up[(size_t)(dout0 + col) * FIXD + fb + kt + q * 4];
            Bs[q * 4 + 0][sc] = v.x;
            Bs[q * 4 + 1][sc] = v.y;
            Bs[q * 4 + 2][sc] = v.z;
            Bs[q * 4 + 3][sc] = v.w;
        }
        __syncthreads();
        #pragma unroll
        for (int k = 0; k < 16; k++) {
            const float4 a  = *(const float4*)&As[k][rbase];
            const float4 ba = *(const float4*)&Bs[k][bread];
            const float4 bb = *(const float4*)&Bs[k][bread + 4];
            const float av[4] = {a.x, a.y, a.z, a.w};
            const float bv[8] = {ba.x, ba.y, ba.z, ba.w, bb.x, bb.y, bb.z, bb.w};
            #pragma unroll
            for (int i = 0; i < 4; i++)
                #pragma unroll
                for (int j = 0; j < 8; j++)
                    acc[i][j] = fmaf(av[i], bv[j], acc[i][j]);
        }
        __syncthreads();
    }
    #pragma unroll
    for (int i = 0; i < 4; i++) {
        float4 o0, o1;
        o0.x = acc[i][0]; o0.y = acc[i][1]; o0.z = acc[i][2]; o0.w = acc[i][3];
        o1.x = acc[i][4]; o1.y = acc[i][5]; o1.z = acc[i][6]; o1.w = acc[i][7];
        float* tr = &Tab[(size_t)((seg << 10) + k0 + rbase + i) * DIN + dout0 + cgrp * 8];
        *(float4*)tr = o0;
        *(float4*)(tr + 4) = o1;
    }
}

// ---------------- K7b: gather-add scatter to output --------------------------
__global__ __launch_bounds__(256) void k_scatter(const float* __restrict__ Tab,
                                                 const unsigned long long* __restrict__ best,
                                                 float* __restrict__ out) {
    __shared__ float Ls[64][65];
    const int dt = blockIdx.x;
    const int wt = blockIdx.y;
    const int b  = blockIdx.z;
    const int dout0 = dt * 64, w0 = wt * 64;
    const int wlim = (WW - w0 < 64) ? (WW - w0) : 64;
    const int tid = threadIdx.x;
    const int wi = tid >> 2, q = tid & 3;

    if (wi < wlim) {
        const int w = w0 + wi;
        const int s = w & 3;
        const int t = w >> 2;
        const int gEt[4] = {0, 1, 3, 4};
        const int gOt[4] = {1, 2, 4, 5};
        int ce = (int)(unsigned)best[gEt[s] * NV + b * TT + t];
        int co = (int)(unsigned)best[gOt[s] * NV + b * TT + t];
        size_t rowE = (size_t)(((2 * s) << 10) + ce) * DIN;
        size_t rowO = (size_t)(((2 * s + 1) << 10) + co) * DIN;
        #pragma unroll
        for (int rep = 0; rep < 4; rep++) {
            const int doff = rep * 16 + q * 4;
            const float4 a = *(const float4*)&Tab[rowE + dout0 + doff];
            const float4 c = *(const float4*)&Tab[rowO + dout0 + doff];
            Ls[wi][doff + 0] = a.x + c.x;
            Ls[wi][doff + 1] = a.y + c.y;
            Ls[wi][doff + 2] = a.z + c.z;
            Ls[wi][doff + 3] = a.w + c.w;
        }
    }
    __syncthreads();
    const size_t obase = (size_t)b * (CC * HH * WW) + (size_t)dout0 * WW + w0;
    #pragma unroll
    for (int i = 0; i < 16; i++) {
        int flat = tid + i * 256;
        int dr = flat >> 6, wj = flat & 63;
        if (wj < wlim) out[obase + (size_t)dr * WW + wj] = Ls[wj][dr];
    }
}

// ---------------- K8: finalize loss scalar -----------------------------------
__global__ void k_finish(const float* __restrict__ lossAcc, float* __restrict__ out) {
    if (threadIdx.x == 0)
        out[58982400] = lossAcc[0] * (0.25f / 29491200.0f);
}

extern "C" void kernel_launch(void* const* d_in, const int* in_sizes, int n_in,
                              void* d_out, int out_size, void* d_ws, size_t ws_size,
                              hipStream_t stream) {
    const float* z      = (const float*)d_in[0];
    const float* w_down = (const float*)d_in[1];
    const float* w_up   = (const float*)d_in[2];
    const float* emb    = (const float*)d_in[3];
    float* out = (float*)d_out;

    float* ws    = (float*)d_ws;
    float* Y     = ws + Y_OFF;
    float* Tab   = ws + Y_OFF;        // overlays Y after rescore/fallback
    float* ET    = ws + ET_OFF;
    float* norms = ws + NORM_OFF;
    unsigned long long* best = (unsigned long long*)(ws + BEST_OFF);
    float* lossA = ws + LOSS_OFF;
    float* znorm = ws + ZN_OFF;
    unsigned* umin  = (unsigned*)(ws + UMIN_OFF);
    unsigned* cnt   = (unsigned*)(ws + CNT_OFF);
    unsigned* maxnU = (unsigned*)(ws + MAXN_OFF);
    unsigned* list_ = (unsigned*)(ws + LIST_OFF);
    unsigned short* Ybf = (unsigned short*)(ws + YBF_OFF);
    unsigned short* Ebf = (unsigned short*)(ws + EBF_OFF);

    hipMemsetAsync(best, 0xFF, (size_t)GG * NV * sizeof(unsigned long long), stream);
    hipMemsetAsync(umin, 0xFF, (size_t)GG * NV * sizeof(unsigned), stream);
    hipMemsetAsync(cnt, 0, (size_t)GG * NV * sizeof(unsigned), stream);
    hipMemsetAsync(maxnU, 0, 64, stream);
    hipMemsetAsync(lossA, 0, sizeof(float), stream);

    dim3 gdown(3, 300);
    k_gemm_down<<<gdown, 256, 0, stream>>>(z, w_down, Y);

    k_transpose<<<(GG * KK * DD + 255) / 256, 256, 0, stream>>>(emb, ET);
    k_norms<<<GG * KK, 64, 0, stream>>>(ET, norms, maxnU);

    k_ysplit<<<GG * NV / 4, 256, 0, stream>>>(Y, Ybf, znorm);
    k_esplit<<<GG * KK * DD / (256 * 8), 256, 0, stream>>>(ET, Ebf);

    dim3 gdist(8, 75, GG);
    k_dist3<1><<<gdist, 256, 0, stream>>>(Ybf, Ebf, norms, znorm, maxnU, umin, cnt, list_);
    k_dist3<2><<<gdist, 256, 0, stream>>>(Ybf, Ebf, norms, znorm, maxnU, umin, cnt, list_);

    k_rescore<<<GG * NV, 64, 0, stream>>>(Y, ET, norms, cnt, list_, best);
    k_fallback<<<GG * NV, 256, 0, stream>>>(Y, ET, norms, cnt, best);

    k_sumloss<<<225, 256, 0, stream>>>(best, znorm, lossA);

    dim3 gtab(16, 12, 8);
    k_table<<<gtab, 256, 0, stream>>>(ET, w_up, Tab);

    dim3 gsc(24, 19, 32);
    k_scatter<<<gsc, 256, 0, stream>>>(Tab, best, out);

    k_finish<<<1, 64, 0, stream>>>(lossA, out);
}

// Round 12
// 1971.307 us; speedup vs baseline: 1.0694x; 1.0121x over previous
//
#include <hip/hip_runtime.h>

#define BB 32
#define CC 128
#define HH 12
#define WW 1200
#define DIN 1536
#define FIXD 768
#define OVL 4
#define GG 6
#define DD 512
#define KK 1024
#define TT 300
#define NV 9600        /* B*T vectors per group */
#define MROWS 38400    /* B*W */

// workspace layout (float offsets)
#define Y_OFF     0          /* 29,491,200 floats; Tab overlays this after rescore/fallback */
#define ET_OFF    29491200
#define NORM_OFF  32636928
#define BEST_OFF  32643072   /* 57600 uint64 */
#define LOSS_OFF  32758272
#define ZN_OFF    32758336   /* 57600 */
#define UMIN_OFF  32815936   /* 57600 u32 */
#define CNT_OFF   32873536   /* 57600 u32 */
#define MAXN_OFF  32931136   /* 64 (6 used) */
#define LIST_OFF  32931200   /* 57600*64 u32 */
#define YBF_OFF   36617600   /* 29,491,200 ushort */
#define EBF_OFF   51363200   /* 3,145,728 ushort */

// LDS column swizzle for 128-wide B-side fp32 tiles (placement-only)
#define BSWZ(c) ((c) + 4 * ((c) >> 5))

typedef __attribute__((ext_vector_type(8))) short bf16x8;
typedef __attribute__((ext_vector_type(4))) float f32x4;

static __device__ inline unsigned short f2bf(float x) {
    unsigned u = __float_as_uint(x);
    unsigned r = (u + 0x7fffu + ((u >> 16) & 1u)) >> 16;
    return (unsigned short)r;
}
static __device__ inline unsigned enc32(float s) {
    unsigned u = __float_as_uint(s);
    return (u & 0x80000000u) ? ~u : (u | 0x80000000u);
}

// ---------------- K1: proj_down fp32 GEMM, 128x256 tile, 8x16/thread ---------
// Y[n][f] = sum_k z[b*1843200 + k*1200 + w] * w_down[f*1536+k];  n = b*1200+w
// Per-output accumulation strictly k-sequential (kt outer 16-step, k inner
// 0..15) -> Y bit-identical to R3..R11 (argmin-critical: do NOT change order).
// amdgpu_waves_per_eu(2,3): max=3 pins the register allocator at the 170-VGPR
// budget so the 128-float accumulator stays in registers (R11 spilled: the
// occupancy heuristic chose 84 VGPR + scratch; WRITE_SIZE +30MB, no speedup).
// LDS-pipe math: 6 b128/k/wave (72 cy) vs 128 FMA (256 SIMD-cy) -> at 3
// waves/EU the LDS pipe is ~1.13x subscribed (was 1.5x at 8x8) -> VALU ~85%.
__attribute__((amdgpu_waves_per_eu(2, 3)))
__global__ __launch_bounds__(256) void k_gemm_down(const float* __restrict__ z,
                                                   const float* __restrict__ w_down,
                                                   float* __restrict__ Y) {
    __shared__ float As[16][132];
    __shared__ float Bs[16][320];
    const int n0 = blockIdx.y * 128, f0 = blockIdx.x * 256;
    const int tid = threadIdx.x;
    // A staging: row fixed per thread (128 rows), 8 k-slots (k = ak0 + 2*i)
    const int arow = tid & 127;
    const int ak0 = tid >> 7;           // 0..1
    const int nA = n0 + arow;
    const int bA = nA / WW, wA = nA - bA * WW;
    const size_t zbase = (size_t)bA * (CC * HH * WW) + wA;
    // B staging: col = tid (256 cols), 4 float4 (full 16-k column)
    const int bcol = tid;
    const int bsc = bcol + 4 * (bcol >> 4);
    // compute thread grid 16x16: trow -> 8 rows, tcol -> 16 cols
    const int trow = tid >> 4, tcol = tid & 15;
    const int bread = tcol * 20;        // swizzled base of col group (16 cols)
    float acc[8][16] = {};
    for (int kt = 0; kt < DIN; kt += 16) {
        #pragma unroll
        for (int i = 0; i < 8; i++) {
            const int kk = ak0 + i * 2;
            As[kk][arow] = z[zbase + (size_t)(kt + kk) * WW];
        }
        #pragma unroll
        for (int q = 0; q < 4; q++) {
            const float4 v = *(const float4*)&w_down[(size_t)(f0 + bcol) * DIN + kt + q * 4];
            Bs[q * 4 + 0][bsc] = v.x;
            Bs[q * 4 + 1][bsc] = v.y;
            Bs[q * 4 + 2][bsc] = v.z;
            Bs[q * 4 + 3][bsc] = v.w;
        }
        __syncthreads();
        #pragma unroll
        for (int k = 0; k < 16; k++) {
            float av[8], bv[16];
            *(float4*)&av[0] = *(const float4*)&As[k][trow * 8];
            *(float4*)&av[4] = *(const float4*)&As[k][trow * 8 + 4];
            *(float4*)&bv[0]  = *(const float4*)&Bs[k][bread];
            *(float4*)&bv[4]  = *(const float4*)&Bs[k][bread + 4];
            *(float4*)&bv[8]  = *(const float4*)&Bs[k][bread + 8];
            *(float4*)&bv[12] = *(const float4*)&Bs[k][bread + 12];
            #pragma unroll
            for (int i = 0; i < 8; i++)
                #pragma unroll
                for (int j = 0; j < 16; j++)
                    acc[i][j] = fmaf(av[i], bv[j], acc[i][j]);
        }
        __syncthreads();
    }
    #pragma unroll
    for (int i = 0; i < 8; i++) {
        float* yr = &Y[(size_t)(n0 + trow * 8 + i) * FIXD + f0 + tcol * 16];
        #pragma unroll
        for (int q = 0; q < 4; q++) {
            float4 o;
            o.x = acc[i][q * 4 + 0]; o.y = acc[i][q * 4 + 1];
            o.z = acc[i][q * 4 + 2]; o.w = acc[i][q * 4 + 3];
            *(float4*)(yr + q * 4) = o;
        }
    }
}

// ---------------- K2: transpose codebook emb(g,d,k) -> ET(g,k,d) -------------
__global__ __launch_bounds__(256) void k_transpose(const float* __restrict__ emb,
                                                   float* __restrict__ ET) {
    int i = blockIdx.x * 256 + threadIdx.x;
    if (i >= GG * KK * DD) return;
    int d = i & 511;
    int rem = i >> 9;
    int k = rem & 1023;
    int g = rem >> 10;
    ET[i] = emb[((g * DD + d) << 10) + k];
}

// ---------------- K2b: per-code norms (fp64) + per-group max norm ------------
__global__ __launch_bounds__(64) void k_norms(const float* __restrict__ ET,
                                              float* __restrict__ norms,
                                              unsigned* __restrict__ maxnU) {
    const int code = blockIdx.x;
    const int lane = threadIdx.x;
    const float* row = ET + code * DD;
    double s = 0.0;
    #pragma unroll
    for (int r = 0; r < 8; r++) {
        float v = row[lane + r * 64];
        s += (double)v * (double)v;
    }
    #pragma unroll
    for (int off = 32; off; off >>= 1) s += __shfl_down(s, off);
    if (lane == 0) {
        const float nf = (float)s;
        norms[code] = nf;
        atomicMax(&maxnU[code >> 10], __float_as_uint(nf));
    }
}

// ---------------- K3a: Y -> Ybf[g][v][d] bf16, plus znorm --------------------
__global__ __launch_bounds__(256) void k_ysplit(const float* __restrict__ Y,
                                                unsigned short* __restrict__ Ybf,
                                                float* __restrict__ znorm) {
    const int gv = blockIdx.x * 4 + (threadIdx.x >> 6);   // 0..57599
    const int lane = threadIdx.x & 63;
    const int g = gv / NV, r = gv - g * NV;
    const int b = r / TT, t = r - b * TT;
    const int d0 = lane * 8;
    const int p = g * DD + d0;                 // 8-run never straddles (split at d=256)
    const int sg = p / FIXD, f = p - sg * FIXD;
    const float* yb = &Y[(size_t)((b * WW + t * OVL + sg) * FIXD + f)];
    const float4 y0 = *(const float4*)yb;
    const float4 y1 = *(const float4*)(yb + 4);
    unsigned short h[8];
    h[0] = f2bf(y0.x); h[1] = f2bf(y0.y); h[2] = f2bf(y0.z); h[3] = f2bf(y0.w);
    h[4] = f2bf(y1.x); h[5] = f2bf(y1.y); h[6] = f2bf(y1.z); h[7] = f2bf(y1.w);
    *(uint4*)&Ybf[(size_t)gv * DD + d0] = *(uint4*)&h[0];
    float s = 0.f;
    s = fmaf(y0.x, y0.x, s); s = fmaf(y0.y, y0.y, s);
    s = fmaf(y0.z, y0.z, s); s = fmaf(y0.w, y0.w, s);
    s = fmaf(y1.x, y1.x, s); s = fmaf(y1.y, y1.y, s);
    s = fmaf(y1.z, y1.z, s); s = fmaf(y1.w, y1.w, s);
    #pragma unroll
    for (int off = 32; off; off >>= 1) s += __shfl_down(s, off);
    if (lane == 0) znorm[gv] = s;
}

// ---------------- K3b: ET -> Ebf bf16 ----------------------------------------
__global__ __launch_bounds__(256) void k_esplit(const float* __restrict__ ET,
                                                unsigned short* __restrict__ Ebf) {
    const size_t i8 = ((size_t)blockIdx.x * 256 + threadIdx.x) * 8;  // 1536 blocks
    const float4 a = *(const float4*)&ET[i8];
    const float4 b = *(const float4*)&ET[i8 + 4];
    unsigned short h[8];
    h[0] = f2bf(a.x); h[1] = f2bf(a.y); h[2] = f2bf(a.z); h[3] = f2bf(a.w);
    h[4] = f2bf(b.x); h[5] = f2bf(b.y); h[6] = f2bf(b.z); h[7] = f2bf(b.w);
    *(uint4*)&Ebf[i8] = *(uint4*)&h[0];
}

// ---------------- K4: MFMA approx distances ----------------------------------
// PHASE 1: per-vector approx min over codes -> atomicMin(umin).
// PHASE 2: recompute (deterministic), collect codes with score <= a1 + marg.
// marg = 0.032*sqrt(znorm_v * maxnorm_g) is a rigorous (2x-cushioned) bound on
// 2*(approx-chain) score error -> chain-winner is guaranteed in the list.
// Grid (ct=8 fastest, vt, g): consecutive blocks share the vt Y-slab (L2).
template<int PHASE>
__global__ __launch_bounds__(256) void k_dist3(const unsigned short* __restrict__ Ybf,
                                               const unsigned short* __restrict__ Ebf,
                                               const float* __restrict__ norms,
                                               const float* __restrict__ znorm,
                                               const unsigned* __restrict__ maxnU,
                                               unsigned* __restrict__ umin,
                                               unsigned* __restrict__ cnt,
                                               unsigned* __restrict__ list_) {
    __shared__ unsigned short Ah[128][40], Bh[128][40];
    __shared__ float a1s[128], margs[128];
    const int ct = blockIdx.x;     // 8 (fastest -> Y-slab L2 reuse)
    const int vt = blockIdx.y;     // 75
    const int g  = blockIdx.z;     // 6
    const int v0 = vt * 128, c0 = ct * 128;
    const int tid = threadIdx.x;
    const size_t ybase = ((size_t)g * NV + v0) * DD;
    const size_t ebase = ((size_t)g * KK + c0) * DD;
    const int srow = tid >> 1, sseg = (tid & 1) * 16;
    const int wv = tid >> 6, lane = tid & 63;
    const int wr = wv >> 1, wc = wv & 1;
    const int m0 = wr * 64, n0 = wc * 64;
    const int lr = lane & 15, lq = lane >> 4;

    if (PHASE == 2 && tid < 128) {
        const int gv = g * NV + v0 + tid;
        const unsigned u = umin[gv];
        const unsigned x = (u & 0x80000000u) ? (u & 0x7fffffffu) : ~u;
        a1s[tid] = __uint_as_float(x);
        margs[tid] = 0.032f * sqrtf(znorm[gv] * __uint_as_float(maxnU[g]));
    }

    f32x4 acc[4][4];
    #pragma unroll
    for (int i = 0; i < 4; i++)
        #pragma unroll
        for (int j = 0; j < 4; j++) acc[i][j] = (f32x4){0.f, 0.f, 0.f, 0.f};

    for (int kt = 0; kt < DD; kt += 32) {
        {
            const uint4 a0 = *(const uint4*)&Ybf[ybase + (size_t)srow * DD + kt + sseg];
            const uint4 a1 = *(const uint4*)&Ybf[ybase + (size_t)srow * DD + kt + sseg + 8];
            const uint4 b0 = *(const uint4*)&Ebf[ebase + (size_t)srow * DD + kt + sseg];
            const uint4 b1 = *(const uint4*)&Ebf[ebase + (size_t)srow * DD + kt + sseg + 8];
            *(uint4*)&Ah[srow][sseg]     = a0;
            *(uint4*)&Ah[srow][sseg + 8] = a1;
            *(uint4*)&Bh[srow][sseg]     = b0;
            *(uint4*)&Bh[srow][sseg + 8] = b1;
        }
        __syncthreads();
        bf16x8 ah[4], bh[4];
        #pragma unroll
        for (int i = 0; i < 4; i++) {
            ah[i] = *(bf16x8*)&Ah[m0 + i * 16 + lr][lq * 8];
            bh[i] = *(bf16x8*)&Bh[n0 + i * 16 + lr][lq * 8];
        }
        #pragma unroll
        for (int i = 0; i < 4; i++)
            #pragma unroll
            for (int j = 0; j < 4; j++)
                acc[i][j] = __builtin_amdgcn_mfma_f32_16x16x32_bf16(ah[i], bh[j], acc[i][j], 0, 0, 0);
        __syncthreads();
    }

    float nrmj[4];
    #pragma unroll
    for (int j = 0; j < 4; j++) nrmj[j] = norms[(g << 10) + c0 + n0 + j * 16 + lr];

    #pragma unroll
    for (int i = 0; i < 4; i++) {
        #pragma unroll
        for (int rr = 0; rr < 4; rr++) {
            const int row = m0 + i * 16 + lq * 4 + rr;
            if (PHASE == 1) {
                unsigned kb = 0xFFFFFFFFu;
                #pragma unroll
                for (int j = 0; j < 4; j++) {
                    const unsigned u = enc32(nrmj[j] - 2.0f * acc[i][j][rr]);
                    kb = (u < kb) ? u : kb;
                }
                #pragma unroll
                for (int off = 1; off < 16; off <<= 1) {
                    const unsigned o = __shfl_xor(kb, off);
                    kb = (o < kb) ? o : kb;
                }
                if (lr == 0) atomicMin(&umin[g * NV + v0 + row], kb);
            } else {
                const float thr = a1s[row] + margs[row];
                #pragma unroll
                for (int j = 0; j < 4; j++) {
                    const float sc = nrmj[j] - 2.0f * acc[i][j][rr];
                    if (sc <= thr) {
                        const int gv = g * NV + v0 + row;
                        const unsigned idx = atomicAdd(&cnt[gv], 1u);
                        if (idx < 64u)
                            list_[(size_t)gv * 64 + idx] = (unsigned)(c0 + n0 + j * 16 + lr);
                    }
                }
            }
        }
    }
}

// ---------------- K5: exact rescore of candidates (bit-identical chain) ------
__global__ __launch_bounds__(64) void k_rescore(const float* __restrict__ Y,
                                                const float* __restrict__ ET,
                                                const float* __restrict__ norms,
                                                const unsigned* __restrict__ cnt,
                                                const unsigned* __restrict__ list_,
                                                unsigned long long* __restrict__ best) {
    const int gv = blockIdx.x;
    const unsigned n = cnt[gv];
    if (n == 0u || n > 64u) return;      // n>64 -> fallback kernel
    const int lane = threadIdx.x;
    const int g = gv / NV, r = gv - g * NV;
    const int b = r / TT, t = r - b * TT;
    unsigned long long key = ~0ull;
    if (lane < (int)n) {
        const unsigned c = list_[(size_t)gv * 64 + lane];
        const float* erow = &ET[((size_t)((g << 10) + c)) * DD];
        float s = 0.f;
        for (int d4 = 0; d4 < 128; ++d4) {
            const int p = g * DD + d4 * 4;
            const int sg = p / FIXD, f = p - sg * FIXD;
            const float4 yv = *(const float4*)&Y[(size_t)((b * WW + t * OVL + sg) * FIXD + f)];
            const float4 ev = *(const float4*)&erow[d4 * 4];
            s = fmaf(yv.x, ev.x, s); s = fmaf(yv.y, ev.y, s);
            s = fmaf(yv.z, ev.z, s); s = fmaf(yv.w, ev.w, s);
        }
        const float sc = norms[(g << 10) + c] - 2.0f * s;
        key = ((unsigned long long)enc32(sc) << 32) | c;
    }
    #pragma unroll
    for (int off = 32; off; off >>= 1) {
        const unsigned long long o = __shfl_down(key, off);
        if (o < key) key = o;
    }
    if (lane == 0) best[gv] = key;
}

// ---------------- K5b: exact fallback for overflowed vectors (rare) ----------
__global__ __launch_bounds__(256) void k_fallback(const float* __restrict__ Y,
                                                  const float* __restrict__ ET,
                                                  const float* __restrict__ norms,
                                                  const unsigned* __restrict__ cnt,
                                                  unsigned long long* __restrict__ best) {
    const int gv = blockIdx.x;
    if (cnt[gv] <= 64u) return;
    __shared__ float Yv[512];
    __shared__ unsigned long long red[256];
    const int tid = threadIdx.x;
    const int g = gv / NV, r = gv - g * NV;
    const int b = r / TT, t = r - b * TT;
    if (tid < 128) {
        const int p = g * DD + tid * 4;
        const int sg = p / FIXD, f = p - sg * FIXD;
        *(float4*)&Yv[tid * 4] = *(const float4*)&Y[(size_t)((b * WW + t * OVL + sg) * FIXD + f)];
    }
    __syncthreads();
    unsigned long long kb = ~0ull;
    for (int cc = 0; cc < 4; ++cc) {
        const int c = tid + cc * 256;
        const float* erow = &ET[((size_t)((g << 10) + c)) * DD];
        float s = 0.f;
        for (int d = 0; d < 512; ++d) s = fmaf(Yv[d], erow[d], s);
        const float sc = norms[(g << 10) + c] - 2.0f * s;
        const unsigned long long key = ((unsigned long long)enc32(sc) << 32) | (unsigned)c;
        if (key < kb) kb = key;
    }
    red[tid] = kb;
    __syncthreads();
    for (int off = 128; off; off >>= 1) {
        if (tid < off) { if (red[tid + off] < red[tid]) red[tid] = red[tid + off]; }
        __syncthreads();
    }
    if (tid == 0) best[gv] = red[0];
}

// ---------------- K6: loss = sum_v (best_score_v + |z_v|^2) ------------------
__global__ __launch_bounds__(256) void k_sumloss(const unsigned long long* __restrict__ best,
                                                 const float* __restrict__ znorm,
                                                 float* __restrict__ lossAcc) {
    const int v = blockIdx.x * 256 + threadIdx.x;
    const unsigned long long key = best[v];
    const unsigned u = (unsigned)(key >> 32);
    const unsigned x = (u & 0x80000000u) ? (u & 0x7fffffffu) : ~u;
    float s = __uint_as_float(x) + znorm[v];
    __shared__ float red[256];
    red[threadIdx.x] = s;
    __syncthreads();
    for (int off = 128; off; off >>= 1) {
        if (threadIdx.x < off) red[threadIdx.x] += red[threadIdx.x + off];
        __syncthreads();
    }
    if (threadIdx.x == 0) atomicAdd(lossAcc, red[0]);
}

// ---------------- K7a: per-(segment,code) up-projection table ----------------
__constant__ int SEG_G[8]  = {0, 1, 1, 2, 3, 4, 4, 5};
__constant__ int SEG_D0[8] = {0, 0, 256, 0, 0, 0, 256, 0};
__constant__ int SEG_L[8]  = {512, 256, 256, 512, 512, 256, 256, 512};
__constant__ int SEG_F0[8] = {0, 512, 0, 256, 0, 512, 0, 256};

__global__ __launch_bounds__(256) void k_table(const float* __restrict__ ET,
                                               const float* __restrict__ w_up,
                                               float* __restrict__ Tab) {
    __shared__ float As[16][68];
    __shared__ float Bs[16][140];
    const int bm = blockIdx.x;
    const int bn = blockIdx.y;
    const int seg = blockIdx.z;
    const int g = SEG_G[seg], d0 = SEG_D0[seg], len = SEG_L[seg], fb = SEG_F0[seg];
    const int tid = threadIdx.x;
    const int k0 = bm * 64, dout0 = bn * 128;
    const int arow = tid >> 2, aq = tid & 3;
    const int rbase = (tid >> 4) << 2;
    const int cgrp = tid & 15;
    const int bread = cgrp * 8 + 4 * (cgrp >> 2);
    const float* ETg = ET + (size_t)(g << 10) * DD;
    float acc[4][8] = {};
    for (int kt = 0; kt < len; kt += 16) {
        {
            const float4 v = *(const float4*)&ETg[(size_t)(k0 + arow) * DD + d0 + kt + aq * 4];
            As[aq * 4 + 0][arow] = v.x;
            As[aq * 4 + 1][arow] = v.y;
            As[aq * 4 + 2][arow] = v.z;
            As[aq * 4 + 3][arow] = v.w;
        }
        #pragma unroll
        for (int i = 0; i < 2; i++) {
            int fl = tid + i * 256;
            int col = fl >> 2, q = fl & 3;
            const int sc = BSWZ(col);
            const float4 v = *(const float4*)&w_up[(size_t)(dout0 + col) * FIXD + fb + kt + q * 4];
            Bs[q * 4 + 0][sc] = v.x;
            Bs[q * 4 + 1][sc] = v.y;
            Bs[q * 4 + 2][sc] = v.z;
            Bs[q * 4 + 3][sc] = v.w;
        }
        __syncthreads();
        #pragma unroll
        for (int k = 0; k < 16; k++) {
            const float4 a  = *(const float4*)&As[k][rbase];
            const float4 ba = *(const float4*)&Bs[k][bread];
            const float4 bb = *(const float4*)&Bs[k][bread + 4];
            const float av[4] = {a.x, a.y, a.z, a.w};
            const float bv[8] = {ba.x, ba.y, ba.z, ba.w, bb.x, bb.y, bb.z, bb.w};
            #pragma unroll
            for (int i = 0; i < 4; i++)
                #pragma unroll
                for (int j = 0; j < 8; j++)
                    acc[i][j] = fmaf(av[i], bv[j], acc[i][j]);
        }
        __syncthreads();
    }
    #pragma unroll
    for (int i = 0; i < 4; i++) {
        float4 o0, o1;
        o0.x = acc[i][0]; o0.y = acc[i][1]; o0.z = acc[i][2]; o0.w = acc[i][3];
        o1.x = acc[i][4]; o1.y = acc[i][5]; o1.z = acc[i][6]; o1.w = acc[i][7];
        float* tr = &Tab[(size_t)((seg << 10) + k0 + rbase + i) * DIN + dout0 + cgrp * 8];
        *(float4*)tr = o0;
        *(float4*)(tr + 4) = o1;
    }
}

// ---------------- K7b: gather-add scatter to output --------------------------
__global__ __launch_bounds__(256) void k_scatter(const float* __restrict__ Tab,
                                                 const unsigned long long* __restrict__ best,
                                                 float* __restrict__ out) {
    __shared__ float Ls[64][65];
    const int dt = blockIdx.x;
    const int wt = blockIdx.y;
    const int b  = blockIdx.z;
    const int dout0 = dt * 64, w0 = wt * 64;
    const int wlim = (WW - w0 < 64) ? (WW - w0) : 64;
    const int tid = threadIdx.x;
    const int wi = tid >> 2, q = tid & 3;

    if (wi < wlim) {
        const int w = w0 + wi;
        const int s = w & 3;
        const int t = w >> 2;
        const int gEt[4] = {0, 1, 3, 4};
        const int gOt[4] = {1, 2, 4, 5};
        int ce = (int)(unsigned)best[gEt[s] * NV + b * TT + t];
        int co = (int)(unsigned)best[gOt[s] * NV + b * TT + t];
        size_t rowE = (size_t)(((2 * s) << 10) + ce) * DIN;
        size_t rowO = (size_t)(((2 * s + 1) << 10) + co) * DIN;
        #pragma unroll
        for (int rep = 0; rep < 4; rep++) {
            const int doff = rep * 16 + q * 4;
            const float4 a = *(const float4*)&Tab[rowE + dout0 + doff];
            const float4 c = *(const float4*)&Tab[rowO + dout0 + doff];
            Ls[wi][doff + 0] = a.x + c.x;
            Ls[wi][doff + 1] = a.y + c.y;
            Ls[wi][doff + 2] = a.z + c.z;
            Ls[wi][doff + 3] = a.w + c.w;
        }
    }
    __syncthreads();
    const size_t obase = (size_t)b * (CC * HH * WW) + (size_t)dout0 * WW + w0;
    #pragma unroll
    for (int i = 0; i < 16; i++) {
        int flat = tid + i * 256;
        int dr = flat >> 6, wj = flat & 63;
        if (wj < wlim) out[obase + (size_t)dr * WW + wj] = Ls[wj][dr];
    }
}

// ---------------- K8: finalize loss scalar -----------------------------------
__global__ void k_finish(const float* __restrict__ lossAcc, float* __restrict__ out) {
    if (threadIdx.x == 0)
        out[58982400] = lossAcc[0] * (0.25f / 29491200.0f);
}

extern "C" void kernel_launch(void* const* d_in, const int* in_sizes, int n_in,
                              void* d_out, int out_size, void* d_ws, size_t ws_size,
                              hipStream_t stream) {
    const float* z      = (const float*)d_in[0];
    const float* w_down = (const float*)d_in[1];
    const float* w_up   = (const float*)d_in[2];
    const float* emb    = (const float*)d_in[3];
    float* out = (float*)d_out;

    float* ws    = (float*)d_ws;
    float* Y     = ws + Y_OFF;
    float* Tab   = ws + Y_OFF;        // overlays Y after rescore/fallback
    float* ET    = ws + ET_OFF;
    float* norms = ws + NORM_OFF;
    unsigned long long* best = (unsigned long long*)(ws + BEST_OFF);
    float* lossA = ws + LOSS_OFF;
    float* znorm = ws + ZN_OFF;
    unsigned* umin  = (unsigned*)(ws + UMIN_OFF);
    unsigned* cnt   = (unsigned*)(ws + CNT_OFF);
    unsigned* maxnU = (unsigned*)(ws + MAXN_OFF);
    unsigned* list_ = (unsigned*)(ws + LIST_OFF);
    unsigned short* Ybf = (unsigned short*)(ws + YBF_OFF);
    unsigned short* Ebf = (unsigned short*)(ws + EBF_OFF);

    hipMemsetAsync(best, 0xFF, (size_t)GG * NV * sizeof(unsigned long long), stream);
    hipMemsetAsync(umin, 0xFF, (size_t)GG * NV * sizeof(unsigned), stream);
    hipMemsetAsync(cnt, 0, (size_t)GG * NV * sizeof(unsigned), stream);
    hipMemsetAsync(maxnU, 0, 64, stream);
    hipMemsetAsync(lossA, 0, sizeof(float), stream);

    dim3 gdown(3, 300);
    k_gemm_down<<<gdown, 256, 0, stream>>>(z, w_down, Y);

    k_transpose<<<(GG * KK * DD + 255) / 256, 256, 0, stream>>>(emb, ET);
    k_norms<<<GG * KK, 64, 0, stream>>>(ET, norms, maxnU);

    k_ysplit<<<GG * NV / 4, 256, 0, stream>>>(Y, Ybf, znorm);
    k_esplit<<<GG * KK * DD / (256 * 8), 256, 0, stream>>>(ET, Ebf);

    dim3 gdist(8, 75, GG);
    k_dist3<1><<<gdist, 256, 0, stream>>>(Ybf, Ebf, norms, znorm, maxnU, umin, cnt, list_);
    k_dist3<2><<<gdist, 256, 0, stream>>>(Ybf, Ebf, norms, znorm, maxnU, umin, cnt, list_);

    k_rescore<<<GG * NV, 64, 0, stream>>>(Y, ET, norms, cnt, list_, best);
    k_fallback<<<GG * NV, 256, 0, stream>>>(Y, ET, norms, cnt, best);

    k_sumloss<<<225, 256, 0, stream>>>(best, znorm, lossA);

    dim3 gtab(16, 12, 8);
    k_table<<<gtab, 256, 0, stream>>>(ET, w_up, Tab);

    dim3 gsc(24, 19, 32);
    k_scatter<<<gsc, 256, 0, stream>>>(Tab, best, out);

    k_finish<<<1, 64, 0, stream>>>(lossA, out);
}